// Round 21
// baseline (66.928 us; speedup 1.0000x reference)
//
#include <hip/hip_runtime.h>
#include <hip/hip_bf16.h>
#include <math.h>

#define NUMC 10000
#define DIMS 128
#define SZM  50
#define FD   512
#define NB   64
#define NL   200
#define NTOK (NB*NL)
#define NGP  8      // group-pairs in scan (blocks.y); 16 effective m-groups
#define MG   4      // m's per group (64 padded; w=0 beyond 49)
#define NPR  8      // combined partials stored / summed by fp
#define CH   10     // steps per staged chunk (scan): 20 chunks of 10

typedef unsigned short u16;
typedef __attribute__((ext_vector_type(8))) short bf16x8;
typedef __attribute__((ext_vector_type(8))) unsigned short u16x8;
typedef __attribute__((ext_vector_type(4))) float f32x4;

// ws layout (float offsets)
#define OFF_K   ((size_t)0)                           // (unused fp32 k region, kept for layout stability)
#define OFF_W   (OFF_K  + (size_t)NTOK*DIMS)          // [NTOK][64], m-major 0..49, 50..63 zeroed
#define OFF_E   (OFF_W  + (size_t)NTOK*64)
#define OFF_A   (OFF_E  + (size_t)NTOK*DIMS)
#define OFF_KBF (OFF_A  + (size_t)NTOK*DIMS)          // bf16 k [NTOK][128] (u16) = NTOK*64 floats
#define OFF_PRF (OFF_KBF+ (size_t)NTOK*64)            // bf16 partials [NPR][NTOK][128] = NTOK*512 floats
#define OFF_PKF (OFF_PRF+ (size_t)NTOK*512)           // packed bf16 weights (u16)
// u16 offsets within pack region:
#define PK_W1 0
#define PK_W2 65536      // 16 ks * 8 nb * 64 lanes * 8
#define PK_WE 131072
#define PK_WA 147456     // 4*8*64*8 = 16384 each
#define PK_MK 163840     // 4*4*64*8 = 8192
#define PK_WF 172032     // 8*8*64*8 = 32768

__device__ __forceinline__ float sigmoidf_(float x){ return 1.0f/(1.0f+expf(-x)); }

__device__ __forceinline__ u16 f2bf(float f){
    unsigned int b = __float_as_uint(f);
    b += 0x7fffu + ((b >> 16) & 1u);
    return (u16)(b >> 16);
}
__device__ __forceinline__ float bf2f(u16 h){
    unsigned int b = ((unsigned int)h) << 16;
    return __uint_as_float(b);
}
// async global->LDS, 16B per lane; LDS dest = uniform base + lane*16; global src per-lane
__device__ __forceinline__ void gl_lds16(const float* g, float* l){
    __builtin_amdgcn_global_load_lds(
        (const __attribute__((address_space(1))) unsigned int*)g,
        (__attribute__((address_space(3))) unsigned int*)l, 16, 0, 0);
}

// ---------------- pack kernel: W[K][128] fp32 -> B-fragment-order bf16 ----------------
__device__ __forceinline__ void pack_one(const float* __restrict__ W, u16* __restrict__ P, int u, int nbw){
    int l = u & 63; int t = u >> 6; int nb = t & (nbw-1); int ks = t / nbw;
    int col = nb*16 + (l & 15);
    int kb  = ks*32 + ((l >> 4) << 3);
    u16* dst = P + (size_t)u*8;
    #pragma unroll
    for (int j=0;j<8;j++) dst[j] = f2bf(W[(size_t)(kb+j)*DIMS + col]);
}

__global__ __launch_bounds__(256) void pack_kernel(
    const float* __restrict__ W1, const float* __restrict__ W2,
    const float* __restrict__ We, const float* __restrict__ Wa,
    const float* __restrict__ Mk, const float* __restrict__ Wf,
    u16* __restrict__ W1p, u16* __restrict__ W2p,
    u16* __restrict__ Wep, u16* __restrict__ Wap,
    u16* __restrict__ Mkp, u16* __restrict__ Wfp)
{
    int gid = blockIdx.x*256 + threadIdx.x;
    if      (gid <  8192) pack_one(W1, W1p, gid,        8);
    else if (gid < 16384) pack_one(W2, W2p, gid- 8192,  8);
    else if (gid < 18432) pack_one(We, Wep, gid-16384,  8);
    else if (gid < 20480) pack_one(Wa, Wap, gid-18432,  8);
    else if (gid < 21504){
        int u = gid - 20480;
        int l = u & 63; int t = u >> 6; int nb = t & 3; int ks = t >> 2;
        int col = nb*16 + (l & 15);
        int kb  = ks*32 + ((l >> 4) << 3);
        u16* dst = Mkp + (size_t)u*8;
        #pragma unroll
        for (int j=0;j<8;j++) dst[j] = (col < SZM) ? f2bf(Mk[(size_t)col*DIMS + kb + j]) : (u16)0;
    }
    else if (gid < 25600) pack_one(Wf, Wfp, gid-21504, 8);   // K=256
}

// ---------------- prep: MFMA GEMMs, K split across 2 wave-sets (512 threads) ----------------
// waves 0-3: K in [0,256); waves 4-7: K in [256,512). Each set stages its own
// 4 chunks; set 1 publishes accumulators via thread-major LDS (conflict-free),
// set 0 combines and runs epilogue/phases 2-3. Doubles waves/CU during the
// latency-bound gather+B-load phase without changing the B:MFMA ratio (r17 lesson).
__device__ __forceinline__ bf16x8 cvt8(f32x4 a, f32x4 b){
    unsigned int r0,r1,r2,r3;
    asm("v_cvt_pk_bf16_f32 %0, %1, %2" : "=v"(r0) : "v"(a[0]), "v"(a[1]));
    asm("v_cvt_pk_bf16_f32 %0, %1, %2" : "=v"(r1) : "v"(a[2]), "v"(a[3]));
    asm("v_cvt_pk_bf16_f32 %0, %1, %2" : "=v"(r2) : "v"(b[0]), "v"(b[1]));
    asm("v_cvt_pk_bf16_f32 %0, %1, %2" : "=v"(r3) : "v"(b[2]), "v"(b[3]));
    union { unsigned int u[4]; bf16x8 v; } o;
    o.u[0]=r0; o.u[1]=r1; o.u[2]=r2; o.u[3]=r3;
    return o.v;
}
#define MFMA(a,b,c) __builtin_amdgcn_mfma_f32_16x16x32_bf16((a),(b),(c),0,0,0)

__global__ __launch_bounds__(512) void prep_kernel(
    const int* __restrict__ q, const int* __restrict__ r,
    const float* __restrict__ k_emb, const float* __restrict__ v_emb,
    const float* __restrict__ b1, const float* __restrict__ b2,
    const float* __restrict__ be, const float* __restrict__ ba,
    const u16* __restrict__ W1p, const u16* __restrict__ W2p,
    const u16* __restrict__ Wep, const u16* __restrict__ Wap,
    const u16* __restrict__ Mkp,
    float* __restrict__ ws, u16* __restrict__ KB)
{
    // LDS arena 64KB:
    //  phase 1: afk [2 set][2 buf][2048] @0 (32KB), afv same @32KB.
    //  post-K : cmb [32][256] @0 (32KB, aliases afk);
    //           skb/svb/lg @32KB (alias afv). Barriers separate live ranges.
    __shared__ __align__(16) char smem[65536];
    __shared__ int qi[32], xi[32];
    float (*afk)[2][2048] = (float(*)[2][2048])(smem);          // [set][buf][2048]
    float (*afv)[2][2048] = (float(*)[2][2048])(smem + 32768);
    float *cmb            = (float*)(smem);                     // [32][256]
    u16   (*skb)[144]     = (u16(*)[144])(smem + 32768);        // 9216B
    u16   (*svb)[144]     = (u16(*)[144])(smem + 32768 + 9216); // 9216B
    float (*lg)[68]       = (float(*)[68])(smem + 32768 + 18432); // 8704B

    const int tid  = threadIdx.x;
    const int base = blockIdx.x * 32;
    if (tid < 32){
        int qq = q[base+tid];
        qi[tid] = qq;
        xi[tid] = qq + NUMC * r[base+tid];
    }
    __syncthreads();

    const int kset = tid >> 8;          // 0: K[0,256)  1: K[256,512)
    const int w    = (tid >> 6) & 3;    // wave within set -> cols [w*32, w*32+32)
    const int l    = tid & 63;
    const int l15  = l & 15;
    const int kgrp = (l >> 4) * 8;
    const int nb0  = 2*w, nb1 = 2*w+1;

    // staging roles (per set): unit u = (w*2+j)*64 + l; token = u&31, f4 = u>>5
    const int su0 = (w*2+0)*64 + l;
    const int su1 = (w*2+1)*64 + l;
    const int st0 = su0 & 31, sf0 = su0 >> 5;
    const int st1 = su1 & 31, sf1 = su1 >> 5;
    const float* kst0 = k_emb + (size_t)qi[st0]*FD + kset*256 + sf0*4;
    const float* kst1 = k_emb + (size_t)qi[st1]*FD + kset*256 + sf1*4;
    const float* vst0 = v_emb + (size_t)xi[st0]*FD + kset*256 + sf0*4;
    const float* vst1 = v_emb + (size_t)xi[st1]*FD + kset*256 + sf1*4;

    #define PSTAGE(bi, c)                                                      \
    {                                                                          \
        gl_lds16(kst0 + (c)*64, &afk[kset][bi][(w*2+0)*256]);                  \
        gl_lds16(kst1 + (c)*64, &afk[kset][bi][(w*2+1)*256]);                  \
        gl_lds16(vst0 + (c)*64, &afv[kset][bi][(w*2+0)*256]);                  \
        gl_lds16(vst1 + (c)*64, &afv[kset][bi][(w*2+1)*256]);                  \
    }

    f32x4 kc00={0,0,0,0},kc01={0,0,0,0},kc10={0,0,0,0},kc11={0,0,0,0};
    f32x4 vc00={0,0,0,0},vc01={0,0,0,0},vc10={0,0,0,0},vc11={0,0,0,0};

    PSTAGE(0, 0)
    __syncthreads();

    int cur = 0;
    for (int c=0; c<4; ++c){            // 4 chunks of 64 floats per set (K=256)
        if (c < 3) PSTAGE(cur^1, c+1)

        #pragma unroll
        for (int ksl=0; ksl<2; ++ksl){
            const int ksg = kset*8 + c*2 + ksl;      // global ks-group
            const int f40 = ksl*8 + (l>>4)*2;
            f32x4 k0a = *(const f32x4*)&afk[kset][cur][((f40  )*32 + l15)*4];
            f32x4 k0b = *(const f32x4*)&afk[kset][cur][((f40+1)*32 + l15)*4];
            f32x4 k1a = *(const f32x4*)&afk[kset][cur][((f40  )*32 + 16+l15)*4];
            f32x4 k1b = *(const f32x4*)&afk[kset][cur][((f40+1)*32 + 16+l15)*4];
            f32x4 v0a = *(const f32x4*)&afv[kset][cur][((f40  )*32 + l15)*4];
            f32x4 v0b = *(const f32x4*)&afv[kset][cur][((f40+1)*32 + l15)*4];
            f32x4 v1a = *(const f32x4*)&afv[kset][cur][((f40  )*32 + 16+l15)*4];
            f32x4 v1b = *(const f32x4*)&afv[kset][cur][((f40+1)*32 + 16+l15)*4];
            bf16x8 ak0 = cvt8(k0a,k0b), ak1 = cvt8(k1a,k1b);
            bf16x8 av0 = cvt8(v0a,v0b), av1 = cvt8(v1a,v1b);
            bf16x8 b10 = *(const bf16x8*)(W1p + ((size_t)(ksg*8+nb0)*64 + l)*8);
            bf16x8 b11 = *(const bf16x8*)(W1p + ((size_t)(ksg*8+nb1)*64 + l)*8);
            bf16x8 b20 = *(const bf16x8*)(W2p + ((size_t)(ksg*8+nb0)*64 + l)*8);
            bf16x8 b21 = *(const bf16x8*)(W2p + ((size_t)(ksg*8+nb1)*64 + l)*8);
            kc00 = MFMA(ak0,b10,kc00); kc01 = MFMA(ak0,b11,kc01);
            kc10 = MFMA(ak1,b10,kc10); kc11 = MFMA(ak1,b11,kc11);
            vc00 = MFMA(av0,b20,vc00); vc01 = MFMA(av0,b21,vc01);
            vc10 = MFMA(av1,b20,vc10); vc11 = MFMA(av1,b21,vc11);
        }
        __syncthreads();   // staging drained + all reads of cur done -> safe to overwrite
        cur ^= 1;
    }
    #undef PSTAGE
    // afk/afv dead -> cmb (set-1 accumulators) and skb/svb/lg become live

    // set 1 publishes accumulators: thread-major layout (conflict-free: lane
    // stride 4B within each j-slice)
    {
        const int p = tid & 255;
        if (kset == 1){
            #pragma unroll
            for (int j=0;j<4;j++){
                cmb[(j    )*256+p]=kc00[j]; cmb[(j+ 4)*256+p]=kc01[j];
                cmb[(j+ 8)*256+p]=kc10[j]; cmb[(j+12)*256+p]=kc11[j];
                cmb[(j+16)*256+p]=vc00[j]; cmb[(j+20)*256+p]=vc01[j];
                cmb[(j+24)*256+p]=vc10[j]; cmb[(j+28)*256+p]=vc11[j];
            }
        }
    }
    __syncthreads();

    if (kset == 0){
        const int p = tid & 255;
        #pragma unroll
        for (int j=0;j<4;j++){
            kc00[j]+=cmb[(j    )*256+p]; kc01[j]+=cmb[(j+ 4)*256+p];
            kc10[j]+=cmb[(j+ 8)*256+p]; kc11[j]+=cmb[(j+12)*256+p];
            vc00[j]+=cmb[(j+16)*256+p]; vc01[j]+=cmb[(j+20)*256+p];
            vc10[j]+=cmb[(j+24)*256+p]; vc11[j]+=cmb[(j+28)*256+p];
        }
        // epilogue: +bias; k -> KB bf16 + skb ; v -> svb bf16
        int c0 = w*32 + l15, c1 = w*32 + 16 + l15;
        float bk0 = b1[c0], bk1 = b1[c1], bv0 = b2[c0], bv1 = b2[c1];
        #pragma unroll
        for (int rr=0; rr<4; ++rr){
            int r0 = (l>>4)*4 + rr;
            int r1 = 16 + r0;
            u16 h;
            h = f2bf(kc00[rr]+bk0); skb[r0][c0]=h; KB[(size_t)(base+r0)*DIMS+c0]=h;
            h = f2bf(kc01[rr]+bk1); skb[r0][c1]=h; KB[(size_t)(base+r0)*DIMS+c1]=h;
            h = f2bf(kc10[rr]+bk0); skb[r1][c0]=h; KB[(size_t)(base+r1)*DIMS+c0]=h;
            h = f2bf(kc11[rr]+bk1); skb[r1][c1]=h; KB[(size_t)(base+r1)*DIMS+c1]=h;
            svb[r0][c0]=f2bf(vc00[rr]+bv0);
            svb[r0][c1]=f2bf(vc01[rr]+bv1);
            svb[r1][c0]=f2bf(vc10[rr]+bv0);
            svb[r1][c1]=f2bf(vc11[rr]+bv1);
        }
    }
    __syncthreads();

    if (kset == 0){
        // ---- phase 2a: logits = k @ Mk^T ----
        f32x4 lc0={0,0,0,0}, lc1={0,0,0,0};
        #pragma unroll
        for (int ks=0; ks<4; ++ks){
            bf16x8 a0 = *(const bf16x8*)&skb[l15   ][ks*32+kgrp];
            bf16x8 a1 = *(const bf16x8*)&skb[16+l15][ks*32+kgrp];
            bf16x8 bm = *(const bf16x8*)(Mkp + ((size_t)(ks*4+w)*64 + l)*8);
            lc0 = MFMA(a0,bm,lc0);
            lc1 = MFMA(a1,bm,lc1);
        }
        int cm = w*16 + l15;
        #pragma unroll
        for (int rr=0; rr<4; ++rr){
            int r0 = (l>>4)*4 + rr;
            lg[r0   ][cm] = lc0[rr];
            lg[16+r0][cm] = lc1[rr];
        }

        // ---- phase 2b: e = sigmoid(v@We+be), a = tanh(v@Wa+ba) ----
        f32x4 ec00={0,0,0,0},ec01={0,0,0,0},ec10={0,0,0,0},ec11={0,0,0,0};
        f32x4 ac00={0,0,0,0},ac01={0,0,0,0},ac10={0,0,0,0},ac11={0,0,0,0};
        #pragma unroll
        for (int ks=0; ks<4; ++ks){
            bf16x8 a0 = *(const bf16x8*)&svb[l15   ][ks*32+kgrp];
            bf16x8 a1 = *(const bf16x8*)&svb[16+l15][ks*32+kgrp];
            bf16x8 e0 = *(const bf16x8*)(Wep + ((size_t)(ks*8+nb0)*64 + l)*8);
            bf16x8 e1 = *(const bf16x8*)(Wep + ((size_t)(ks*8+nb1)*64 + l)*8);
            bf16x8 a0w= *(const bf16x8*)(Wap + ((size_t)(ks*8+nb0)*64 + l)*8);
            bf16x8 a1w= *(const bf16x8*)(Wap + ((size_t)(ks*8+nb1)*64 + l)*8);
            ec00 = MFMA(a0,e0,ec00); ec01 = MFMA(a0,e1,ec01);
            ec10 = MFMA(a1,e0,ec10); ec11 = MFMA(a1,e1,ec11);
            ac00 = MFMA(a0,a0w,ac00); ac01 = MFMA(a0,a1w,ac01);
            ac10 = MFMA(a1,a0w,ac10); ac11 = MFMA(a1,a1w,ac11);
        }
        int c0 = w*32 + l15, c1 = w*32 + 16 + l15;
        float beE0 = be[c0], beE1 = be[c1], baA0 = ba[c0], baA1 = ba[c1];
        #pragma unroll
        for (int rr=0; rr<4; ++rr){
            int r0 = (l>>4)*4 + rr;
            int r1 = 16 + r0;
            ws[OFF_E+(size_t)(base+r0)*DIMS+c0] = sigmoidf_(ec00[rr]+beE0);
            ws[OFF_E+(size_t)(base+r0)*DIMS+c1] = sigmoidf_(ec01[rr]+beE1);
            ws[OFF_E+(size_t)(base+r1)*DIMS+c0] = sigmoidf_(ec10[rr]+beE0);
            ws[OFF_E+(size_t)(base+r1)*DIMS+c1] = sigmoidf_(ec11[rr]+beE1);
            ws[OFF_A+(size_t)(base+r0)*DIMS+c0] = tanhf(ac00[rr]+baA0);
            ws[OFF_A+(size_t)(base+r0)*DIMS+c1] = tanhf(ac01[rr]+baA1);
            ws[OFF_A+(size_t)(base+r1)*DIMS+c0] = tanhf(ac10[rr]+baA0);
            ws[OFF_A+(size_t)(base+r1)*DIMS+c1] = tanhf(ac11[rr]+baA1);
        }
    }
    __syncthreads();

    // ---- phase 3: softmax over m; zero-fill padded slots 50..63 ----
    if (tid < 256){
        const int t  = tid >> 3;
        const int ml = tid & 7;
        float v[7]; float mx = -1e30f;
        #pragma unroll
        for (int j=0;j<7;j++){
            int m = ml + j*8;
            float x = (m < SZM) ? lg[t][m] : -1e30f;
            v[j] = x; mx = fmaxf(mx, x);
        }
        #pragma unroll
        for (int o=1;o<8;o<<=1) mx = fmaxf(mx, __shfl_xor(mx, o));
        float ex[7]; float sm = 0.f;
        #pragma unroll
        for (int j=0;j<7;j++){
            int m = ml + j*8;
            ex[j] = (m < SZM) ? expf(v[j]-mx) : 0.f;
            sm += ex[j];
        }
        #pragma unroll
        for (int o=1;o<8;o<<=1) sm += __shfl_xor(sm, o);
        float inv = 1.f/sm;
        #pragma unroll
        for (int j=0;j<8;j++){
            int m = ml + j*8;
            float val = (j<7 && m<SZM) ? ex[j]*inv : 0.f;
            if (m < 64) ws[OFF_W + (size_t)(base+t)*64 + m] = val;
        }
    }
}

// ---------------- scan: paired 256-thr blocks; w via uniform-addr LDS broadcast ----------------
__global__ __launch_bounds__(256) void scan_kernel(const float* __restrict__ Mv0,
                                                   float* __restrict__ ws,
                                                   u16* __restrict__ PRB)
{
    __shared__ float e_lds[2][CH*DIMS];    // 10KB
    __shared__ float a_lds[2][CH*DIMS];    // 10KB
    __shared__ float w_lds[2][768];        // 6KB (CH*64=640 padded to 3x256)
    __shared__ float rt_lds[2][CH*DIMS];   // 10KB (pair-combine, dbuf vs barrier)

    const int b    = blockIdx.x;
    const int gp   = blockIdx.y;           // group pair 0..7
    const int tid  = threadIdx.x;
    const int d    = tid & 127;
    const int half = tid >> 7;             // 0 = lower group (stores), 1 = upper
    const int lane = tid & 63;
    const int wid  = tid >> 6;             // 0..3

    const float* Eg = ws + OFF_E + (size_t)b*NL*DIMS;
    const float* Ag = ws + OFF_A + (size_t)b*NL*DIMS;
    const float* Wg = ws + OFF_W + (size_t)b*NL*64;
    u16* prb = PRB + ((size_t)gp*NTOK + (size_t)b*NL)*DIMS + d;

    const int mg0 = (2*gp + half)*MG;
    float Mv[MG];
    #pragma unroll
    for (int m=0;m<MG;m++) Mv[m] = (mg0+m < SZM) ? Mv0[(mg0+m)*DIMS + d] : 0.f;

    #define STAGE(bi, t0)                                                          \
    {                                                                              \
        const float* Eb = Eg + (size_t)(t0)*DIMS;                                  \
        const float* Ab = Ag + (size_t)(t0)*DIMS;                                  \
        const float* Wb = Wg + (size_t)(t0)*64;                                    \
        for (int i = wid; i < CH*DIMS/256; i += 4){                                \
            gl_lds16(Eb + i*256 + lane*4, &e_lds[bi][i*256]);                      \
            gl_lds16(Ab + i*256 + lane*4, &a_lds[bi][i*256]);                      \
        }                                                                          \
        for (int i = wid; i < 3; i += 4){                                          \
            gl_lds16(Wb + i*256 + lane*4, &w_lds[bi][i*256]);                      \
        }                                                                          \
    }

    STAGE(0, 0)
    __syncthreads();

    float rts[CH];
    int cur = 0;
    for (int c = 0; c < NL/CH; ++c){
        if (c > 0 && half == 0){
            #pragma unroll
            for (int s=0;s<CH;s++)
                prb[(size_t)((c-1)*CH+s)*DIMS] = f2bf(rts[s] + rt_lds[cur^1][s*DIMS+d]);
        }
        if (c+1 < NL/CH) STAGE(cur^1, (c+1)*CH)

        float ev[CH], av[CH];
        #pragma unroll
        for (int s=0;s<CH;s++){
            ev[s] = e_lds[cur][s*DIMS + d];
            av[s] = a_lds[cur][s*DIMS + d];
        }
        #pragma unroll
        for (int s=0;s<CH;s++){
            float rt0=0.f, rt1=0.f;
            #pragma unroll
            for (int m=0;m<MG;m++){
                float cc = w_lds[cur][s*64 + mg0 + m];  // wave-uniform -> broadcast
                float u  = fmaf(-ev[s], Mv[m], av[s]);
                if (m&1) rt1 = fmaf(cc, Mv[m], rt1);
                else     rt0 = fmaf(cc, Mv[m], rt0);
                Mv[m] = fmaf(cc, u, Mv[m]);
            }
            rts[s] = rt0+rt1;
        }
        if (half == 1){
            #pragma unroll
            for (int s=0;s<CH;s++) rt_lds[cur][s*DIMS+d] = rts[s];
        }
        __syncthreads();
        cur ^= 1;
    }
    if (half == 0){
        #pragma unroll
        for (int s=0;s<CH;s++)
            prb[(size_t)((NL-CH)+s)*DIMS] = f2bf(rts[s] + rt_lds[cur^1][s*DIMS+d]);
    }
    #undef STAGE
}

// ---------------- fp: MFMA GEMM, A = [sum8(reads) | k] bf16 ----------------
__global__ __launch_bounds__(256) void fp_kernel(
    const u16* __restrict__ PRB, const u16* __restrict__ KB,
    const u16* __restrict__ Wfp,
    const float* __restrict__ bf, const float* __restrict__ Wp,
    const float* __restrict__ bp, float* __restrict__ out)
{
    __shared__ __align__(16) u16 sA[32][264];   // [token][0..127 reads | 128..255 k]
    __shared__ float pf[32][132];

    const int tid  = threadIdx.x;
    const int base = blockIdx.x * 32;

    {
        const int t  = tid >> 3;
        const int p8 = tid & 7;
        const size_t tok = (size_t)base + t;
        #pragma unroll
        for (int v=0; v<2; ++v){
            const int d0 = p8*16 + v*8;
            float s[8] = {0,0,0,0,0,0,0,0};
            #pragma unroll
            for (int g=0; g<NPR; ++g){
                u16x8 x = *(const u16x8*)(PRB + ((size_t)g*NTOK + tok)*DIMS + d0);
                #pragma unroll
                for (int j=0;j<8;j++) s[j] += bf2f(x[j]);
            }
            u16x8 o;
            #pragma unroll
            for (int j=0;j<8;j++) o[j] = f2bf(s[j]);
            *(u16x8*)&sA[t][d0] = o;
            *(u16x8*)&sA[t][128+d0] = *(const u16x8*)(KB + tok*DIMS + d0);
        }
    }
    __syncthreads();

    const int w    = tid >> 6;
    const int l    = tid & 63;
    const int l15  = l & 15;
    const int kgrp = (l >> 4) * 8;
    const int nb0  = 2*w, nb1 = 2*w+1;

    f32x4 c00={0,0,0,0},c01={0,0,0,0},c10={0,0,0,0},c11={0,0,0,0};
    #pragma unroll
    for (int ks=0; ks<8; ++ks){
        bf16x8 a0 = *(const bf16x8*)&sA[l15   ][ks*32+kgrp];
        bf16x8 a1 = *(const bf16x8*)&sA[16+l15][ks*32+kgrp];
        bf16x8 b0 = *(const bf16x8*)(Wfp + ((size_t)(ks*8+nb0)*64 + l)*8);
        bf16x8 b1 = *(const bf16x8*)(Wfp + ((size_t)(ks*8+nb1)*64 + l)*8);
        c00 = MFMA(a0,b0,c00); c01 = MFMA(a0,b1,c01);
        c10 = MFMA(a1,b0,c10); c11 = MFMA(a1,b1,c11);
    }
    {
        int cc0 = w*32 + l15, cc1 = w*32 + 16 + l15;
        float bf0 = bf[cc0], bf1 = bf[cc1];
        float wp0 = Wp[cc0], wp1 = Wp[cc1];
        #pragma unroll
        for (int rr=0; rr<4; ++rr){
            int r0 = (l>>4)*4 + rr;
            int r1 = 16 + r0;
            pf[r0][cc0] = tanhf(c00[rr]+bf0)*wp0;
            pf[r0][cc1] = tanhf(c01[rr]+bf1)*wp1;
            pf[r1][cc0] = tanhf(c10[rr]+bf0)*wp0;
            pf[r1][cc1] = tanhf(c11[rr]+bf1)*wp1;
        }
    }
    __syncthreads();

    {
        const int t  = tid >> 3;
        const int ml = tid & 7;
        float s = 0.f;
        #pragma unroll
        for (int j=0;j<16;j++) s += pf[t][ml + j*8];
        #pragma unroll
        for (int o=1;o<8;o<<=1) s += __shfl_xor(s, o);
        if (ml == 0) out[base+t] = sigmoidf_(s + bp[0]);
    }
}

extern "C" void kernel_launch(void* const* d_in, const int* in_sizes, int n_in,
                              void* d_out, int out_size, void* d_ws, size_t ws_size,
                              hipStream_t stream)
{
    const int*   q     = (const int*)  d_in[0];
    const int*   r     = (const int*)  d_in[1];
    /* d_in[2] = diff (unused) */
    const float* k_emb = (const float*)d_in[3];
    const float* v_emb = (const float*)d_in[4];
    const float* W1    = (const float*)d_in[5];
    const float* b1    = (const float*)d_in[6];
    const float* W2    = (const float*)d_in[7];
    const float* b2    = (const float*)d_in[8];
    const float* Mk    = (const float*)d_in[9];
    const float* Mv0   = (const float*)d_in[10];
    const float* We    = (const float*)d_in[11];
    const float* be    = (const float*)d_in[12];
    const float* Wa    = (const float*)d_in[13];
    const float* ba    = (const float*)d_in[14];
    const float* Wf    = (const float*)d_in[15];
    const float* bf    = (const float*)d_in[16];
    const float* Wp    = (const float*)d_in[17];
    const float* bp    = (const float*)d_in[18];

    float* ws  = (float*)d_ws;
    float* out = (float*)d_out;
    u16* KB  = (u16*)(ws + OFF_KBF);
    u16* PRB = (u16*)(ws + OFF_PRF);
    u16* pk  = (u16*)(ws + OFF_PKF);
    u16* W1p = pk + PK_W1;
    u16* W2p = pk + PK_W2;
    u16* Wep = pk + PK_WE;
    u16* Wap = pk + PK_WA;
    u16* Mkp = pk + PK_MK;
    u16* Wfp = pk + PK_WF;

    pack_kernel<<<100, 256, 0, stream>>>(W1,W2,We,Wa,Mk,Wf, W1p,W2p,Wep,Wap,Mkp,Wfp);
    prep_kernel<<<NTOK/32, 512, 0, stream>>>(q,r,k_emb,v_emb,b1,b2,be,ba,W1p,W2p,Wep,Wap,Mkp,ws,KB);
    scan_kernel<<<dim3(NB,NGP), 256, 0, stream>>>(Mv0, ws, PRB);
    fp_kernel<<<NTOK/32, 256, 0, stream>>>(PRB, KB, Wfp, bf, Wp, bp, out);
}

// Round 22
// 66.466 us; speedup vs baseline: 1.0070x; 1.0070x over previous
//
#include <hip/hip_runtime.h>
#include <hip/hip_bf16.h>
#include <math.h>

#define NUMC 10000
#define DIMS 128
#define SZM  50
#define FD   512
#define NB   64
#define NL   200
#define NTOK (NB*NL)
#define NGP  8      // group-pairs in scan (blocks.y); 16 effective m-groups
#define MG   4      // m's per group (64 padded; w=0 beyond 49)
#define NPR  8      // combined partials stored / summed by fp
#define CH   10     // steps per staged chunk (scan): 20 chunks of 10

typedef unsigned short u16;
typedef __attribute__((ext_vector_type(8))) short bf16x8;
typedef __attribute__((ext_vector_type(8))) unsigned short u16x8;
typedef __attribute__((ext_vector_type(4))) float f32x4;

// ws layout (float offsets)
#define OFF_K   ((size_t)0)                           // (unused fp32 k region, kept for layout stability)
#define OFF_W   (OFF_K  + (size_t)NTOK*DIMS)          // [NTOK][64], m-major 0..49, 50..63 zeroed
#define OFF_E   (OFF_W  + (size_t)NTOK*64)
#define OFF_A   (OFF_E  + (size_t)NTOK*DIMS)
#define OFF_KBF (OFF_A  + (size_t)NTOK*DIMS)          // bf16 k [NTOK][128] (u16) = NTOK*64 floats
#define OFF_PRF (OFF_KBF+ (size_t)NTOK*64)            // bf16 partials [NPR][NTOK][128] = NTOK*512 floats
#define OFF_PKF (OFF_PRF+ (size_t)NTOK*512)           // packed bf16 weights (u16)
// u16 offsets within pack region:
#define PK_W1 0
#define PK_W2 65536      // 16 ks * 8 nb * 64 lanes * 8
#define PK_WE 131072
#define PK_WA 147456     // 4*8*64*8 = 16384 each
#define PK_MK 163840     // 4*4*64*8 = 8192
#define PK_WF 172032     // 8*8*64*8 = 32768

__device__ __forceinline__ float sigmoidf_(float x){ return 1.0f/(1.0f+expf(-x)); }

__device__ __forceinline__ u16 f2bf(float f){
    unsigned int b = __float_as_uint(f);
    b += 0x7fffu + ((b >> 16) & 1u);
    return (u16)(b >> 16);
}
__device__ __forceinline__ float bf2f(u16 h){
    unsigned int b = ((unsigned int)h) << 16;
    return __uint_as_float(b);
}
// async global->LDS, 16B per lane; LDS dest = uniform base + lane*16; global src per-lane
__device__ __forceinline__ void gl_lds16(const float* g, float* l){
    __builtin_amdgcn_global_load_lds(
        (const __attribute__((address_space(1))) unsigned int*)g,
        (__attribute__((address_space(3))) unsigned int*)l, 16, 0, 0);
}

// ---------------- pack kernel: W[K][128] fp32 -> B-fragment-order bf16 ----------------
__device__ __forceinline__ void pack_one(const float* __restrict__ W, u16* __restrict__ P, int u, int nbw){
    int l = u & 63; int t = u >> 6; int nb = t & (nbw-1); int ks = t / nbw;
    int col = nb*16 + (l & 15);
    int kb  = ks*32 + ((l >> 4) << 3);
    u16* dst = P + (size_t)u*8;
    #pragma unroll
    for (int j=0;j<8;j++) dst[j] = f2bf(W[(size_t)(kb+j)*DIMS + col]);
}

__global__ __launch_bounds__(256) void pack_kernel(
    const float* __restrict__ W1, const float* __restrict__ W2,
    const float* __restrict__ We, const float* __restrict__ Wa,
    const float* __restrict__ Mk, const float* __restrict__ Wf,
    u16* __restrict__ W1p, u16* __restrict__ W2p,
    u16* __restrict__ Wep, u16* __restrict__ Wap,
    u16* __restrict__ Mkp, u16* __restrict__ Wfp)
{
    int gid = blockIdx.x*256 + threadIdx.x;
    if      (gid <  8192) pack_one(W1, W1p, gid,        8);
    else if (gid < 16384) pack_one(W2, W2p, gid- 8192,  8);
    else if (gid < 18432) pack_one(We, Wep, gid-16384,  8);
    else if (gid < 20480) pack_one(Wa, Wap, gid-18432,  8);
    else if (gid < 21504){
        int u = gid - 20480;
        int l = u & 63; int t = u >> 6; int nb = t & 3; int ks = t >> 2;
        int col = nb*16 + (l & 15);
        int kb  = ks*32 + ((l >> 4) << 3);
        u16* dst = Mkp + (size_t)u*8;
        #pragma unroll
        for (int j=0;j<8;j++) dst[j] = (col < SZM) ? f2bf(Mk[(size_t)col*DIMS + kb + j]) : (u16)0;
    }
    else if (gid < 25600) pack_one(Wf, Wfp, gid-21504, 8);   // K=256
}

// ---------------- prep: MFMA GEMMs, coalesced XOR-swizzled A-gather staging ----------------
// Staging layout change vs round 20: unit u = token*16 + slot (token-major), so
// each 16-lane subgroup reads ONE token's contiguous 256B chunk (8 cache lines
// per gl_lds16 vs 32 before). Bank conflicts on the MFMA-side reads are killed
// by permuting the GLOBAL source (f4_src = slot ^ (token&7)) and applying the
// same XOR on the LDS read (m201 both-sides swizzle; LDS dest stays linear).
// Per-ds_read_b128 bank load is exactly 8 dwords/bank (wave64 minimum).
__device__ __forceinline__ bf16x8 cvt8(f32x4 a, f32x4 b){
    unsigned int r0,r1,r2,r3;
    asm("v_cvt_pk_bf16_f32 %0, %1, %2" : "=v"(r0) : "v"(a[0]), "v"(a[1]));
    asm("v_cvt_pk_bf16_f32 %0, %1, %2" : "=v"(r1) : "v"(a[2]), "v"(a[3]));
    asm("v_cvt_pk_bf16_f32 %0, %1, %2" : "=v"(r2) : "v"(b[0]), "v"(b[1]));
    asm("v_cvt_pk_bf16_f32 %0, %1, %2" : "=v"(r3) : "v"(b[2]), "v"(b[3]));
    union { unsigned int u[4]; bf16x8 v; } o;
    o.u[0]=r0; o.u[1]=r1; o.u[2]=r2; o.u[3]=r3;
    return o.v;
}
#define MFMA(a,b,c) __builtin_amdgcn_mfma_f32_16x16x32_bf16((a),(b),(c),0,0,0)

__global__ __launch_bounds__(256) void prep_kernel(
    const int* __restrict__ q, const int* __restrict__ r,
    const float* __restrict__ k_emb, const float* __restrict__ v_emb,
    const float* __restrict__ b1, const float* __restrict__ b2,
    const float* __restrict__ be, const float* __restrict__ ba,
    const u16* __restrict__ W1p, const u16* __restrict__ W2p,
    const u16* __restrict__ Wep, const u16* __restrict__ Wap,
    const u16* __restrict__ Mkp,
    float* __restrict__ ws, u16* __restrict__ KB)
{
    // LDS arena: phase 1 (afk/afv, 32KB) strictly precedes phase 2/3 (skb/svb/lg,
    // 27KB), separated by barriers -> alias them. 59KB -> 33KB: 4 blocks/CU.
    __shared__ __align__(16) char smem[32768];
    __shared__ int qi[32], xi[32];
    float (*afk)[2048] = (float(*)[2048])(smem);            // [2][2048] 16KB
    float (*afv)[2048] = (float(*)[2048])(smem + 16384);    // [2][2048] 16KB
    u16   (*skb)[144]  = (u16(*)[144])(smem);               // 9216B
    u16   (*svb)[144]  = (u16(*)[144])(smem + 9216);        // 9216B
    float (*lg)[68]    = (float(*)[68])(smem + 18432);      // 8704B

    const int tid  = threadIdx.x;
    const int base = blockIdx.x * 32;
    if (tid < 32){
        int qq = q[base+tid];
        qi[tid] = qq;
        xi[tid] = qq + NUMC * r[base+tid];
    }
    __syncthreads();

    const int w    = tid >> 6;
    const int l    = tid & 63;
    const int l15  = l & 15;

    // staging roles: issue j covers tokens 8w+4j..+3; 16 lanes per token read
    // its 256B chunk in XOR-permuted 16B units.
    const int tk0 = 8*w +     (l >> 4);     // token for issue 0
    const int tk1 = 8*w + 4 + (l >> 4);     // token for issue 1
    const int sl  = l & 15;                 // LDS slot within token
    const int f0  = sl ^ (tk0 & 7);         // global f4 unit loaded into slot
    const int f1  = sl ^ (tk1 & 7);
    const float* kst0 = k_emb + (size_t)qi[tk0]*FD + f0*4;
    const float* kst1 = k_emb + (size_t)qi[tk1]*FD + f1*4;
    const float* vst0 = v_emb + (size_t)xi[tk0]*FD + f0*4;
    const float* vst1 = v_emb + (size_t)xi[tk1]*FD + f1*4;

    #define PSTAGE(bi, c)                                                      \
    {                                                                          \
        gl_lds16(kst0 + (c)*64, &afk[bi][(w*2+0)*256]);                        \
        gl_lds16(kst1 + (c)*64, &afk[bi][(w*2+1)*256]);                        \
        gl_lds16(vst0 + (c)*64, &afv[bi][(w*2+0)*256]);                        \
        gl_lds16(vst1 + (c)*64, &afv[bi][(w*2+1)*256]);                        \
    }

    f32x4 kc00={0,0,0,0},kc01={0,0,0,0},kc10={0,0,0,0},kc11={0,0,0,0};
    f32x4 vc00={0,0,0,0},vc01={0,0,0,0},vc10={0,0,0,0},vc11={0,0,0,0};

    PSTAGE(0, 0)
    __syncthreads();

    const int kgrp = (l >> 4) * 8;
    const int nb0  = 2*w, nb1 = 2*w+1;
    const int x0 = l15*64;          // token l15 row base (floats) in afk/afv
    const int x1 = (16+l15)*64;     // token 16+l15 ((16+l15)&7 == l15&7)
    const int sw = l15 & 7;         // read-side XOR key

    int cur = 0;
    for (int c=0; c<8; ++c){
        if (c < 7) PSTAGE(cur^1, c+1)

        #pragma unroll
        for (int ksl=0; ksl<2; ++ksl){
            const int ksg = c*2 + ksl;
            const int f40 = ksl*8 + (l>>4)*2;
            const int o0 = ((f40  ) ^ sw)*4;
            const int o1 = ((f40+1) ^ sw)*4;
            f32x4 k0a = *(const f32x4*)&afk[cur][x0 + o0];
            f32x4 k0b = *(const f32x4*)&afk[cur][x0 + o1];
            f32x4 k1a = *(const f32x4*)&afk[cur][x1 + o0];
            f32x4 k1b = *(const f32x4*)&afk[cur][x1 + o1];
            f32x4 v0a = *(const f32x4*)&afv[cur][x0 + o0];
            f32x4 v0b = *(const f32x4*)&afv[cur][x0 + o1];
            f32x4 v1a = *(const f32x4*)&afv[cur][x1 + o0];
            f32x4 v1b = *(const f32x4*)&afv[cur][x1 + o1];
            bf16x8 ak0 = cvt8(k0a,k0b), ak1 = cvt8(k1a,k1b);
            bf16x8 av0 = cvt8(v0a,v0b), av1 = cvt8(v1a,v1b);
            bf16x8 b10 = *(const bf16x8*)(W1p + ((size_t)(ksg*8+nb0)*64 + l)*8);
            bf16x8 b11 = *(const bf16x8*)(W1p + ((size_t)(ksg*8+nb1)*64 + l)*8);
            bf16x8 b20 = *(const bf16x8*)(W2p + ((size_t)(ksg*8+nb0)*64 + l)*8);
            bf16x8 b21 = *(const bf16x8*)(W2p + ((size_t)(ksg*8+nb1)*64 + l)*8);
            kc00 = MFMA(ak0,b10,kc00); kc01 = MFMA(ak0,b11,kc01);
            kc10 = MFMA(ak1,b10,kc10); kc11 = MFMA(ak1,b11,kc11);
            vc00 = MFMA(av0,b20,vc00); vc01 = MFMA(av0,b21,vc01);
            vc10 = MFMA(av1,b20,vc10); vc11 = MFMA(av1,b21,vc11);
        }
        __syncthreads();   // staging drained + all reads of cur done -> safe to overwrite
        cur ^= 1;
    }
    #undef PSTAGE
    // after final barrier, afk/afv dead -> skb/svb/lg (aliased) become live

    // epilogue: +bias; k -> KB bf16 + skb ; v -> svb bf16
    {
        int c0 = w*32 + l15, c1 = w*32 + 16 + l15;
        float bk0 = b1[c0], bk1 = b1[c1], bv0 = b2[c0], bv1 = b2[c1];
        #pragma unroll
        for (int rr=0; rr<4; ++rr){
            int r0 = (l>>4)*4 + rr;
            int r1 = 16 + r0;
            u16 h;
            h = f2bf(kc00[rr]+bk0); skb[r0][c0]=h; KB[(size_t)(base+r0)*DIMS+c0]=h;
            h = f2bf(kc01[rr]+bk1); skb[r0][c1]=h; KB[(size_t)(base+r0)*DIMS+c1]=h;
            h = f2bf(kc10[rr]+bk0); skb[r1][c0]=h; KB[(size_t)(base+r1)*DIMS+c0]=h;
            h = f2bf(kc11[rr]+bk1); skb[r1][c1]=h; KB[(size_t)(base+r1)*DIMS+c1]=h;
            svb[r0][c0]=f2bf(vc00[rr]+bv0);
            svb[r0][c1]=f2bf(vc01[rr]+bv1);
            svb[r1][c0]=f2bf(vc10[rr]+bv0);
            svb[r1][c1]=f2bf(vc11[rr]+bv1);
        }
    }
    __syncthreads();

    // ---- phase 2a: logits = k @ Mk^T ----
    {
        f32x4 lc0={0,0,0,0}, lc1={0,0,0,0};
        #pragma unroll
        for (int ks=0; ks<4; ++ks){
            bf16x8 a0 = *(const bf16x8*)&skb[l15   ][ks*32+kgrp];
            bf16x8 a1 = *(const bf16x8*)&skb[16+l15][ks*32+kgrp];
            bf16x8 bm = *(const bf16x8*)(Mkp + ((size_t)(ks*4+w)*64 + l)*8);
            lc0 = MFMA(a0,bm,lc0);
            lc1 = MFMA(a1,bm,lc1);
        }
        int cm = w*16 + l15;
        #pragma unroll
        for (int rr=0; rr<4; ++rr){
            int r0 = (l>>4)*4 + rr;
            lg[r0   ][cm] = lc0[rr];
            lg[16+r0][cm] = lc1[rr];
        }
    }

    // ---- phase 2b: e = sigmoid(v@We+be), a = tanh(v@Wa+ba) ----
    {
        f32x4 ec00={0,0,0,0},ec01={0,0,0,0},ec10={0,0,0,0},ec11={0,0,0,0};
        f32x4 ac00={0,0,0,0},ac01={0,0,0,0},ac10={0,0,0,0},ac11={0,0,0,0};
        #pragma unroll
        for (int ks=0; ks<4; ++ks){
            bf16x8 a0 = *(const bf16x8*)&svb[l15   ][ks*32+kgrp];
            bf16x8 a1 = *(const bf16x8*)&svb[16+l15][ks*32+kgrp];
            bf16x8 e0 = *(const bf16x8*)(Wep + ((size_t)(ks*8+nb0)*64 + l)*8);
            bf16x8 e1 = *(const bf16x8*)(Wep + ((size_t)(ks*8+nb1)*64 + l)*8);
            bf16x8 a0w= *(const bf16x8*)(Wap + ((size_t)(ks*8+nb0)*64 + l)*8);
            bf16x8 a1w= *(const bf16x8*)(Wap + ((size_t)(ks*8+nb1)*64 + l)*8);
            ec00 = MFMA(a0,e0,ec00); ec01 = MFMA(a0,e1,ec01);
            ec10 = MFMA(a1,e0,ec10); ec11 = MFMA(a1,e1,ec11);
            ac00 = MFMA(a0,a0w,ac00); ac01 = MFMA(a0,a1w,ac01);
            ac10 = MFMA(a1,a0w,ac10); ac11 = MFMA(a1,a1w,ac11);
        }
        int c0 = w*32 + l15, c1 = w*32 + 16 + l15;
        float beE0 = be[c0], beE1 = be[c1], baA0 = ba[c0], baA1 = ba[c1];
        #pragma unroll
        for (int rr=0; rr<4; ++rr){
            int r0 = (l>>4)*4 + rr;
            int r1 = 16 + r0;
            ws[OFF_E+(size_t)(base+r0)*DIMS+c0] = sigmoidf_(ec00[rr]+beE0);
            ws[OFF_E+(size_t)(base+r0)*DIMS+c1] = sigmoidf_(ec01[rr]+beE1);
            ws[OFF_E+(size_t)(base+r1)*DIMS+c0] = sigmoidf_(ec10[rr]+beE0);
            ws[OFF_E+(size_t)(base+r1)*DIMS+c1] = sigmoidf_(ec11[rr]+beE1);
            ws[OFF_A+(size_t)(base+r0)*DIMS+c0] = tanhf(ac00[rr]+baA0);
            ws[OFF_A+(size_t)(base+r0)*DIMS+c1] = tanhf(ac01[rr]+baA1);
            ws[OFF_A+(size_t)(base+r1)*DIMS+c0] = tanhf(ac10[rr]+baA0);
            ws[OFF_A+(size_t)(base+r1)*DIMS+c1] = tanhf(ac11[rr]+baA1);
        }
    }
    __syncthreads();

    // ---- phase 3: softmax over m; zero-fill padded slots 50..63 ----
    {
        const int t  = tid >> 3;
        const int ml = tid & 7;
        float v[7]; float mx = -1e30f;
        #pragma unroll
        for (int j=0;j<7;j++){
            int m = ml + j*8;
            float x = (m < SZM) ? lg[t][m] : -1e30f;
            v[j] = x; mx = fmaxf(mx, x);
        }
        #pragma unroll
        for (int o=1;o<8;o<<=1) mx = fmaxf(mx, __shfl_xor(mx, o));
        float ex[7]; float sm = 0.f;
        #pragma unroll
        for (int j=0;j<7;j++){
            int m = ml + j*8;
            ex[j] = (m < SZM) ? expf(v[j]-mx) : 0.f;
            sm += ex[j];
        }
        #pragma unroll
        for (int o=1;o<8;o<<=1) sm += __shfl_xor(sm, o);
        float inv = 1.f/sm;
        #pragma unroll
        for (int j=0;j<8;j++){
            int m = ml + j*8;
            float val = (j<7 && m<SZM) ? ex[j]*inv : 0.f;
            if (m < 64) ws[OFF_W + (size_t)(base+t)*64 + m] = val;
        }
    }
}

// ---------------- scan: paired 256-thr blocks; w via uniform-addr LDS broadcast ----------------
__global__ __launch_bounds__(256) void scan_kernel(const float* __restrict__ Mv0,
                                                   float* __restrict__ ws,
                                                   u16* __restrict__ PRB)
{
    __shared__ float e_lds[2][CH*DIMS];    // 10KB
    __shared__ float a_lds[2][CH*DIMS];    // 10KB
    __shared__ float w_lds[2][768];        // 6KB (CH*64=640 padded to 3x256)
    __shared__ float rt_lds[2][CH*DIMS];   // 10KB (pair-combine, dbuf vs barrier)

    const int b    = blockIdx.x;
    const int gp   = blockIdx.y;           // group pair 0..7
    const int tid  = threadIdx.x;
    const int d    = tid & 127;
    const int half = tid >> 7;             // 0 = lower group (stores), 1 = upper
    const int lane = tid & 63;
    const int wid  = tid >> 6;             // 0..3

    const float* Eg = ws + OFF_E + (size_t)b*NL*DIMS;
    const float* Ag = ws + OFF_A + (size_t)b*NL*DIMS;
    const float* Wg = ws + OFF_W + (size_t)b*NL*64;
    u16* prb = PRB + ((size_t)gp*NTOK + (size_t)b*NL)*DIMS + d;

    const int mg0 = (2*gp + half)*MG;
    float Mv[MG];
    #pragma unroll
    for (int m=0;m<MG;m++) Mv[m] = (mg0+m < SZM) ? Mv0[(mg0+m)*DIMS + d] : 0.f;

    #define STAGE(bi, t0)                                                          \
    {                                                                              \
        const float* Eb = Eg + (size_t)(t0)*DIMS;                                  \
        const float* Ab = Ag + (size_t)(t0)*DIMS;                                  \
        const float* Wb = Wg + (size_t)(t0)*64;                                    \
        for (int i = wid; i < CH*DIMS/256; i += 4){                                \
            gl_lds16(Eb + i*256 + lane*4, &e_lds[bi][i*256]);                      \
            gl_lds16(Ab + i*256 + lane*4, &a_lds[bi][i*256]);                      \
        }                                                                          \
        for (int i = wid; i < 3; i += 4){                                          \
            gl_lds16(Wb + i*256 + lane*4, &w_lds[bi][i*256]);                      \
        }                                                                          \
    }

    STAGE(0, 0)
    __syncthreads();

    float rts[CH];
    int cur = 0;
    for (int c = 0; c < NL/CH; ++c){
        if (c > 0 && half == 0){
            #pragma unroll
            for (int s=0;s<CH;s++)
                prb[(size_t)((c-1)*CH+s)*DIMS] = f2bf(rts[s] + rt_lds[cur^1][s*DIMS+d]);
        }
        if (c+1 < NL/CH) STAGE(cur^1, (c+1)*CH)

        float ev[CH], av[CH];
        #pragma unroll
        for (int s=0;s<CH;s++){
            ev[s] = e_lds[cur][s*DIMS + d];
            av[s] = a_lds[cur][s*DIMS + d];
        }
        #pragma unroll
        for (int s=0;s<CH;s++){
            float rt0=0.f, rt1=0.f;
            #pragma unroll
            for (int m=0;m<MG;m++){
                float cc = w_lds[cur][s*64 + mg0 + m];  // wave-uniform -> broadcast
                float u  = fmaf(-ev[s], Mv[m], av[s]);
                if (m&1) rt1 = fmaf(cc, Mv[m], rt1);
                else     rt0 = fmaf(cc, Mv[m], rt0);
                Mv[m] = fmaf(cc, u, Mv[m]);
            }
            rts[s] = rt0+rt1;
        }
        if (half == 1){
            #pragma unroll
            for (int s=0;s<CH;s++) rt_lds[cur][s*DIMS+d] = rts[s];
        }
        __syncthreads();
        cur ^= 1;
    }
    if (half == 0){
        #pragma unroll
        for (int s=0;s<CH;s++)
            prb[(size_t)((NL-CH)+s)*DIMS] = f2bf(rts[s] + rt_lds[cur^1][s*DIMS+d]);
    }
    #undef STAGE
}

// ---------------- fp: MFMA GEMM, A = [sum8(reads) | k] bf16 ----------------
__global__ __launch_bounds__(256) void fp_kernel(
    const u16* __restrict__ PRB, const u16* __restrict__ KB,
    const u16* __restrict__ Wfp,
    const float* __restrict__ bf, const float* __restrict__ Wp,
    const float* __restrict__ bp, float* __restrict__ out)
{
    __shared__ __align__(16) u16 sA[32][264];   // [token][0..127 reads | 128..255 k]
    __shared__ float pf[32][132];

    const int tid  = threadIdx.x;
    const int base = blockIdx.x * 32;

    {
        const int t  = tid >> 3;
        const int p8 = tid & 7;
        const size_t tok = (size_t)base + t;
        #pragma unroll
        for (int v=0; v<2; ++v){
            const int d0 = p8*16 + v*8;
            float s[8] = {0,0,0,0,0,0,0,0};
            #pragma unroll
            for (int g=0; g<NPR; ++g){
                u16x8 x = *(const u16x8*)(PRB + ((size_t)g*NTOK + tok)*DIMS + d0);
                #pragma unroll
                for (int j=0;j<8;j++) s[j] += bf2f(x[j]);
            }
            u16x8 o;
            #pragma unroll
            for (int j=0;j<8;j++) o[j] = f2bf(s[j]);
            *(u16x8*)&sA[t][d0] = o;
            *(u16x8*)&sA[t][128+d0] = *(const u16x8*)(KB + tok*DIMS + d0);
        }
    }
    __syncthreads();

    const int w    = tid >> 6;
    const int l    = tid & 63;
    const int l15  = l & 15;
    const int kgrp = (l >> 4) * 8;
    const int nb0  = 2*w, nb1 = 2*w+1;

    f32x4 c00={0,0,0,0},c01={0,0,0,0},c10={0,0,0,0},c11={0,0,0,0};
    #pragma unroll
    for (int ks=0; ks<8; ++ks){
        bf16x8 a0 = *(const bf16x8*)&sA[l15   ][ks*32+kgrp];
        bf16x8 a1 = *(const bf16x8*)&sA[16+l15][ks*32+kgrp];
        bf16x8 b0 = *(const bf16x8*)(Wfp + ((size_t)(ks*8+nb0)*64 + l)*8);
        bf16x8 b1 = *(const bf16x8*)(Wfp + ((size_t)(ks*8+nb1)*64 + l)*8);
        c00 = MFMA(a0,b0,c00); c01 = MFMA(a0,b1,c01);
        c10 = MFMA(a1,b0,c10); c11 = MFMA(a1,b1,c11);
    }
    {
        int cc0 = w*32 + l15, cc1 = w*32 + 16 + l15;
        float bf0 = bf[cc0], bf1 = bf[cc1];
        float wp0 = Wp[cc0], wp1 = Wp[cc1];
        #pragma unroll
        for (int rr=0; rr<4; ++rr){
            int r0 = (l>>4)*4 + rr;
            int r1 = 16 + r0;
            pf[r0][cc0] = tanhf(c00[rr]+bf0)*wp0;
            pf[r0][cc1] = tanhf(c01[rr]+bf1)*wp1;
            pf[r1][cc0] = tanhf(c10[rr]+bf0)*wp0;
            pf[r1][cc1] = tanhf(c11[rr]+bf1)*wp1;
        }
    }
    __syncthreads();

    {
        const int t  = tid >> 3;
        const int ml = tid & 7;
        float s = 0.f;
        #pragma unroll
        for (int j=0;j<16;j++) s += pf[t][ml + j*8];
        #pragma unroll
        for (int o=1;o<8;o<<=1) s += __shfl_xor(s, o);
        if (ml == 0) out[base+t] = sigmoidf_(s + bp[0]);
    }
}

extern "C" void kernel_launch(void* const* d_in, const int* in_sizes, int n_in,
                              void* d_out, int out_size, void* d_ws, size_t ws_size,
                              hipStream_t stream)
{
    const int*   q     = (const int*)  d_in[0];
    const int*   r     = (const int*)  d_in[1];
    /* d_in[2] = diff (unused) */
    const float* k_emb = (const float*)d_in[3];
    const float* v_emb = (const float*)d_in[4];
    const float* W1    = (const float*)d_in[5];
    const float* b1    = (const float*)d_in[6];
    const float* W2    = (const float*)d_in[7];
    const float* b2    = (const float*)d_in[8];
    const float* Mk    = (const float*)d_in[9];
    const float* Mv0   = (const float*)d_in[10];
    const float* We    = (const float*)d_in[11];
    const float* be    = (const float*)d_in[12];
    const float* Wa    = (const float*)d_in[13];
    const float* ba    = (const float*)d_in[14];
    const float* Wf    = (const float*)d_in[15];
    const float* bf    = (const float*)d_in[16];
    const float* Wp    = (const float*)d_in[17];
    const float* bp    = (const float*)d_in[18];

    float* ws  = (float*)d_ws;
    float* out = (float*)d_out;
    u16* KB  = (u16*)(ws + OFF_KBF);
    u16* PRB = (u16*)(ws + OFF_PRF);
    u16* pk  = (u16*)(ws + OFF_PKF);
    u16* W1p = pk + PK_W1;
    u16* W2p = pk + PK_W2;
    u16* Wep = pk + PK_WE;
    u16* Wap = pk + PK_WA;
    u16* Mkp = pk + PK_MK;
    u16* Wfp = pk + PK_WF;

    pack_kernel<<<100, 256, 0, stream>>>(W1,W2,We,Wa,Mk,Wf, W1p,W2p,Wep,Wap,Mkp,Wfp);
    prep_kernel<<<NTOK/32, 256, 0, stream>>>(q,r,k_emb,v_emb,b1,b2,be,ba,W1p,W2p,Wep,Wap,Mkp,ws,KB);
    scan_kernel<<<dim3(NB,NGP), 256, 0, stream>>>(Mv0, ws, PRB);
    fp_kernel<<<NTOK/32, 256, 0, stream>>>(PRB, KB, Wfp, bf, Wp, bp, out);
}

// Round 23
// 64.554 us; speedup vs baseline: 1.0368x; 1.0296x over previous
//
#include <hip/hip_runtime.h>
#include <hip/hip_bf16.h>
#include <math.h>

#define NUMC 10000
#define DIMS 128
#define SZM  50
#define FD   512
#define NB   64
#define NL   200
#define NTOK (NB*NL)
#define NGQ  4      // group-quads in scan (blocks.y); 16 effective m-groups
#define MG   4      // m's per group (64 padded; w=0 beyond 49)
#define NPR  4      // combined partials stored / summed by fp
#define CH   10     // steps per staged chunk (scan): 20 chunks of 10

typedef unsigned short u16;
typedef __attribute__((ext_vector_type(8))) short bf16x8;
typedef __attribute__((ext_vector_type(8))) unsigned short u16x8;
typedef __attribute__((ext_vector_type(4))) float f32x4;

// ws layout (float offsets)
#define OFF_K   ((size_t)0)                           // (unused fp32 k region, kept for layout stability)
#define OFF_W   (OFF_K  + (size_t)NTOK*DIMS)          // [NTOK][64], m-major 0..49, 50..63 zeroed
#define OFF_E   (OFF_W  + (size_t)NTOK*64)
#define OFF_A   (OFF_E  + (size_t)NTOK*DIMS)
#define OFF_KBF (OFF_A  + (size_t)NTOK*DIMS)          // bf16 k [NTOK][128] (u16) = NTOK*64 floats
#define OFF_PRF (OFF_KBF+ (size_t)NTOK*64)            // bf16 partials [NPR][NTOK][128] (region sized for 8, uses 4)
#define OFF_PKF (OFF_PRF+ (size_t)NTOK*512)           // packed bf16 weights (u16)
// u16 offsets within pack region:
#define PK_W1 0
#define PK_W2 65536      // 16 ks * 8 nb * 64 lanes * 8
#define PK_WE 131072
#define PK_WA 147456     // 4*8*64*8 = 16384 each
#define PK_MK 163840     // 4*4*64*8 = 8192
#define PK_WF 172032     // 8*8*64*8 = 32768

__device__ __forceinline__ float sigmoidf_(float x){ return 1.0f/(1.0f+expf(-x)); }

__device__ __forceinline__ u16 f2bf(float f){
    unsigned int b = __float_as_uint(f);
    b += 0x7fffu + ((b >> 16) & 1u);
    return (u16)(b >> 16);
}
__device__ __forceinline__ float bf2f(u16 h){
    unsigned int b = ((unsigned int)h) << 16;
    return __uint_as_float(b);
}
// async global->LDS, 16B per lane; LDS dest = uniform base + lane*16; global src per-lane
__device__ __forceinline__ void gl_lds16(const float* g, float* l){
    __builtin_amdgcn_global_load_lds(
        (const __attribute__((address_space(1))) unsigned int*)g,
        (__attribute__((address_space(3))) unsigned int*)l, 16, 0, 0);
}

// ---------------- pack kernel: W[K][128] fp32 -> B-fragment-order bf16 ----------------
__device__ __forceinline__ void pack_one(const float* __restrict__ W, u16* __restrict__ P, int u, int nbw){
    int l = u & 63; int t = u >> 6; int nb = t & (nbw-1); int ks = t / nbw;
    int col = nb*16 + (l & 15);
    int kb  = ks*32 + ((l >> 4) << 3);
    u16* dst = P + (size_t)u*8;
    #pragma unroll
    for (int j=0;j<8;j++) dst[j] = f2bf(W[(size_t)(kb+j)*DIMS + col]);
}

__global__ __launch_bounds__(256) void pack_kernel(
    const float* __restrict__ W1, const float* __restrict__ W2,
    const float* __restrict__ We, const float* __restrict__ Wa,
    const float* __restrict__ Mk, const float* __restrict__ Wf,
    u16* __restrict__ W1p, u16* __restrict__ W2p,
    u16* __restrict__ Wep, u16* __restrict__ Wap,
    u16* __restrict__ Mkp, u16* __restrict__ Wfp)
{
    int gid = blockIdx.x*256 + threadIdx.x;
    if      (gid <  8192) pack_one(W1, W1p, gid,        8);
    else if (gid < 16384) pack_one(W2, W2p, gid- 8192,  8);
    else if (gid < 18432) pack_one(We, Wep, gid-16384,  8);
    else if (gid < 20480) pack_one(Wa, Wap, gid-18432,  8);
    else if (gid < 21504){
        int u = gid - 20480;
        int l = u & 63; int t = u >> 6; int nb = t & 3; int ks = t >> 2;
        int col = nb*16 + (l & 15);
        int kb  = ks*32 + ((l >> 4) << 3);
        u16* dst = Mkp + (size_t)u*8;
        #pragma unroll
        for (int j=0;j<8;j++) dst[j] = (col < SZM) ? f2bf(Mk[(size_t)col*DIMS + kb + j]) : (u16)0;
    }
    else if (gid < 25600) pack_one(Wf, Wfp, gid-21504, 8);   // K=256
}

// ---------------- prep: MFMA GEMMs, coalesced XOR-swizzled A-gather staging ----------------
__device__ __forceinline__ bf16x8 cvt8(f32x4 a, f32x4 b){
    unsigned int r0,r1,r2,r3;
    asm("v_cvt_pk_bf16_f32 %0, %1, %2" : "=v"(r0) : "v"(a[0]), "v"(a[1]));
    asm("v_cvt_pk_bf16_f32 %0, %1, %2" : "=v"(r1) : "v"(a[2]), "v"(a[3]));
    asm("v_cvt_pk_bf16_f32 %0, %1, %2" : "=v"(r2) : "v"(b[0]), "v"(b[1]));
    asm("v_cvt_pk_bf16_f32 %0, %1, %2" : "=v"(r3) : "v"(b[2]), "v"(b[3]));
    union { unsigned int u[4]; bf16x8 v; } o;
    o.u[0]=r0; o.u[1]=r1; o.u[2]=r2; o.u[3]=r3;
    return o.v;
}
#define MFMA(a,b,c) __builtin_amdgcn_mfma_f32_16x16x32_bf16((a),(b),(c),0,0,0)

__global__ __launch_bounds__(256) void prep_kernel(
    const int* __restrict__ q, const int* __restrict__ r,
    const float* __restrict__ k_emb, const float* __restrict__ v_emb,
    const float* __restrict__ b1, const float* __restrict__ b2,
    const float* __restrict__ be, const float* __restrict__ ba,
    const u16* __restrict__ W1p, const u16* __restrict__ W2p,
    const u16* __restrict__ Wep, const u16* __restrict__ Wap,
    const u16* __restrict__ Mkp,
    float* __restrict__ ws, u16* __restrict__ KB)
{
    __shared__ __align__(16) char smem[32768];
    __shared__ int qi[32], xi[32];
    float (*afk)[2048] = (float(*)[2048])(smem);            // [2][2048] 16KB
    float (*afv)[2048] = (float(*)[2048])(smem + 16384);    // [2][2048] 16KB
    u16   (*skb)[144]  = (u16(*)[144])(smem);               // 9216B
    u16   (*svb)[144]  = (u16(*)[144])(smem + 9216);        // 9216B
    float (*lg)[68]    = (float(*)[68])(smem + 18432);      // 8704B

    const int tid  = threadIdx.x;
    const int base = blockIdx.x * 32;
    if (tid < 32){
        int qq = q[base+tid];
        qi[tid] = qq;
        xi[tid] = qq + NUMC * r[base+tid];
    }
    __syncthreads();

    const int w    = tid >> 6;
    const int l    = tid & 63;
    const int l15  = l & 15;

    const int tk0 = 8*w +     (l >> 4);
    const int tk1 = 8*w + 4 + (l >> 4);
    const int sl  = l & 15;
    const int f0  = sl ^ (tk0 & 7);
    const int f1  = sl ^ (tk1 & 7);
    const float* kst0 = k_emb + (size_t)qi[tk0]*FD + f0*4;
    const float* kst1 = k_emb + (size_t)qi[tk1]*FD + f1*4;
    const float* vst0 = v_emb + (size_t)xi[tk0]*FD + f0*4;
    const float* vst1 = v_emb + (size_t)xi[tk1]*FD + f1*4;

    #define PSTAGE(bi, c)                                                      \
    {                                                                          \
        gl_lds16(kst0 + (c)*64, &afk[bi][(w*2+0)*256]);                        \
        gl_lds16(kst1 + (c)*64, &afk[bi][(w*2+1)*256]);                        \
        gl_lds16(vst0 + (c)*64, &afv[bi][(w*2+0)*256]);                        \
        gl_lds16(vst1 + (c)*64, &afv[bi][(w*2+1)*256]);                        \
    }

    f32x4 kc00={0,0,0,0},kc01={0,0,0,0},kc10={0,0,0,0},kc11={0,0,0,0};
    f32x4 vc00={0,0,0,0},vc01={0,0,0,0},vc10={0,0,0,0},vc11={0,0,0,0};

    PSTAGE(0, 0)
    __syncthreads();

    const int kgrp = (l >> 4) * 8;
    const int nb0  = 2*w, nb1 = 2*w+1;
    const int x0 = l15*64;
    const int x1 = (16+l15)*64;
    const int sw = l15 & 7;

    int cur = 0;
    for (int c=0; c<8; ++c){
        if (c < 7) PSTAGE(cur^1, c+1)

        #pragma unroll
        for (int ksl=0; ksl<2; ++ksl){
            const int ksg = c*2 + ksl;
            const int f40 = ksl*8 + (l>>4)*2;
            const int o0 = ((f40  ) ^ sw)*4;
            const int o1 = ((f40+1) ^ sw)*4;
            f32x4 k0a = *(const f32x4*)&afk[cur][x0 + o0];
            f32x4 k0b = *(const f32x4*)&afk[cur][x0 + o1];
            f32x4 k1a = *(const f32x4*)&afk[cur][x1 + o0];
            f32x4 k1b = *(const f32x4*)&afk[cur][x1 + o1];
            f32x4 v0a = *(const f32x4*)&afv[cur][x0 + o0];
            f32x4 v0b = *(const f32x4*)&afv[cur][x0 + o1];
            f32x4 v1a = *(const f32x4*)&afv[cur][x1 + o0];
            f32x4 v1b = *(const f32x4*)&afv[cur][x1 + o1];
            bf16x8 ak0 = cvt8(k0a,k0b), ak1 = cvt8(k1a,k1b);
            bf16x8 av0 = cvt8(v0a,v0b), av1 = cvt8(v1a,v1b);
            bf16x8 b10 = *(const bf16x8*)(W1p + ((size_t)(ksg*8+nb0)*64 + l)*8);
            bf16x8 b11 = *(const bf16x8*)(W1p + ((size_t)(ksg*8+nb1)*64 + l)*8);
            bf16x8 b20 = *(const bf16x8*)(W2p + ((size_t)(ksg*8+nb0)*64 + l)*8);
            bf16x8 b21 = *(const bf16x8*)(W2p + ((size_t)(ksg*8+nb1)*64 + l)*8);
            kc00 = MFMA(ak0,b10,kc00); kc01 = MFMA(ak0,b11,kc01);
            kc10 = MFMA(ak1,b10,kc10); kc11 = MFMA(ak1,b11,kc11);
            vc00 = MFMA(av0,b20,vc00); vc01 = MFMA(av0,b21,vc01);
            vc10 = MFMA(av1,b20,vc10); vc11 = MFMA(av1,b21,vc11);
        }
        __syncthreads();
        cur ^= 1;
    }
    #undef PSTAGE

    {
        int c0 = w*32 + l15, c1 = w*32 + 16 + l15;
        float bk0 = b1[c0], bk1 = b1[c1], bv0 = b2[c0], bv1 = b2[c1];
        #pragma unroll
        for (int rr=0; rr<4; ++rr){
            int r0 = (l>>4)*4 + rr;
            int r1 = 16 + r0;
            u16 h;
            h = f2bf(kc00[rr]+bk0); skb[r0][c0]=h; KB[(size_t)(base+r0)*DIMS+c0]=h;
            h = f2bf(kc01[rr]+bk1); skb[r0][c1]=h; KB[(size_t)(base+r0)*DIMS+c1]=h;
            h = f2bf(kc10[rr]+bk0); skb[r1][c0]=h; KB[(size_t)(base+r1)*DIMS+c0]=h;
            h = f2bf(kc11[rr]+bk1); skb[r1][c1]=h; KB[(size_t)(base+r1)*DIMS+c1]=h;
            svb[r0][c0]=f2bf(vc00[rr]+bv0);
            svb[r0][c1]=f2bf(vc01[rr]+bv1);
            svb[r1][c0]=f2bf(vc10[rr]+bv0);
            svb[r1][c1]=f2bf(vc11[rr]+bv1);
        }
    }
    __syncthreads();

    {
        f32x4 lc0={0,0,0,0}, lc1={0,0,0,0};
        #pragma unroll
        for (int ks=0; ks<4; ++ks){
            bf16x8 a0 = *(const bf16x8*)&skb[l15   ][ks*32+kgrp];
            bf16x8 a1 = *(const bf16x8*)&skb[16+l15][ks*32+kgrp];
            bf16x8 bm = *(const bf16x8*)(Mkp + ((size_t)(ks*4+w)*64 + l)*8);
            lc0 = MFMA(a0,bm,lc0);
            lc1 = MFMA(a1,bm,lc1);
        }
        int cm = w*16 + l15;
        #pragma unroll
        for (int rr=0; rr<4; ++rr){
            int r0 = (l>>4)*4 + rr;
            lg[r0   ][cm] = lc0[rr];
            lg[16+r0][cm] = lc1[rr];
        }
    }

    {
        f32x4 ec00={0,0,0,0},ec01={0,0,0,0},ec10={0,0,0,0},ec11={0,0,0,0};
        f32x4 ac00={0,0,0,0},ac01={0,0,0,0},ac10={0,0,0,0},ac11={0,0,0,0};
        #pragma unroll
        for (int ks=0; ks<4; ++ks){
            bf16x8 a0 = *(const bf16x8*)&svb[l15   ][ks*32+kgrp];
            bf16x8 a1 = *(const bf16x8*)&svb[16+l15][ks*32+kgrp];
            bf16x8 e0 = *(const bf16x8*)(Wep + ((size_t)(ks*8+nb0)*64 + l)*8);
            bf16x8 e1 = *(const bf16x8*)(Wep + ((size_t)(ks*8+nb1)*64 + l)*8);
            bf16x8 a0w= *(const bf16x8*)(Wap + ((size_t)(ks*8+nb0)*64 + l)*8);
            bf16x8 a1w= *(const bf16x8*)(Wap + ((size_t)(ks*8+nb1)*64 + l)*8);
            ec00 = MFMA(a0,e0,ec00); ec01 = MFMA(a0,e1,ec01);
            ec10 = MFMA(a1,e0,ec10); ec11 = MFMA(a1,e1,ec11);
            ac00 = MFMA(a0,a0w,ac00); ac01 = MFMA(a0,a1w,ac01);
            ac10 = MFMA(a1,a0w,ac10); ac11 = MFMA(a1,a1w,ac11);
        }
        int c0 = w*32 + l15, c1 = w*32 + 16 + l15;
        float beE0 = be[c0], beE1 = be[c1], baA0 = ba[c0], baA1 = ba[c1];
        #pragma unroll
        for (int rr=0; rr<4; ++rr){
            int r0 = (l>>4)*4 + rr;
            int r1 = 16 + r0;
            ws[OFF_E+(size_t)(base+r0)*DIMS+c0] = sigmoidf_(ec00[rr]+beE0);
            ws[OFF_E+(size_t)(base+r0)*DIMS+c1] = sigmoidf_(ec01[rr]+beE1);
            ws[OFF_E+(size_t)(base+r1)*DIMS+c0] = sigmoidf_(ec10[rr]+beE0);
            ws[OFF_E+(size_t)(base+r1)*DIMS+c1] = sigmoidf_(ec11[rr]+beE1);
            ws[OFF_A+(size_t)(base+r0)*DIMS+c0] = tanhf(ac00[rr]+baA0);
            ws[OFF_A+(size_t)(base+r0)*DIMS+c1] = tanhf(ac01[rr]+baA1);
            ws[OFF_A+(size_t)(base+r1)*DIMS+c0] = tanhf(ac10[rr]+baA0);
            ws[OFF_A+(size_t)(base+r1)*DIMS+c1] = tanhf(ac11[rr]+baA1);
        }
    }
    __syncthreads();

    {
        const int t  = tid >> 3;
        const int ml = tid & 7;
        float v[7]; float mx = -1e30f;
        #pragma unroll
        for (int j=0;j<7;j++){
            int m = ml + j*8;
            float x = (m < SZM) ? lg[t][m] : -1e30f;
            v[j] = x; mx = fmaxf(mx, x);
        }
        #pragma unroll
        for (int o=1;o<8;o<<=1) mx = fmaxf(mx, __shfl_xor(mx, o));
        float ex[7]; float sm = 0.f;
        #pragma unroll
        for (int j=0;j<7;j++){
            int m = ml + j*8;
            ex[j] = (m < SZM) ? expf(v[j]-mx) : 0.f;
            sm += ex[j];
        }
        #pragma unroll
        for (int o=1;o<8;o<<=1) sm += __shfl_xor(sm, o);
        float inv = 1.f/sm;
        #pragma unroll
        for (int j=0;j<8;j++){
            int m = ml + j*8;
            float val = (j<7 && m<SZM) ? ex[j]*inv : 0.f;
            if (m < 64) ws[OFF_W + (size_t)(base+t)*64 + m] = val;
        }
    }
}

// ---------------- scan: NGQ=4 quad 512-thr blocks; halves E/A + PRB traffic ----------------
// 256 blocks x 8 waves = 2 waves/SIMD (1 block/CU, 56KB LDS). E/A redundancy
// 8x -> 4x (105 -> 52MB), PRB 26 -> 13MB. Quad-combine via 3 dbuf rt_lds
// buffers (mechanics proven ~neutral in r17; here they buy a traffic halving).
__global__ __launch_bounds__(512) void scan_kernel(const float* __restrict__ Mv0,
                                                   float* __restrict__ ws,
                                                   u16* __restrict__ PRB)
{
    __shared__ float e_lds[2][CH*DIMS];      // 10KB
    __shared__ float a_lds[2][CH*DIMS];      // 10KB
    __shared__ float w_lds[2][768];          // 6KB (CH*64=640 padded to 3x256)
    __shared__ float rt_lds[2][3][CH*DIMS];  // 30KB (quad-combine, dbuf vs barrier)

    const int b    = blockIdx.x;
    const int gq   = blockIdx.y;             // group quad 0..3
    const int tid  = threadIdx.x;
    const int d    = tid & 127;
    const int sub  = tid >> 7;               // 0..3; sub 0 combines+stores
    const int lane = tid & 63;
    const int wid  = tid >> 6;               // 0..7

    const float* Eg = ws + OFF_E + (size_t)b*NL*DIMS;
    const float* Ag = ws + OFF_A + (size_t)b*NL*DIMS;
    const float* Wg = ws + OFF_W + (size_t)b*NL*64;
    u16* prb = PRB + ((size_t)gq*NTOK + (size_t)b*NL)*DIMS + d;

    const int mg0 = (4*gq + sub)*MG;
    float Mv[MG];
    #pragma unroll
    for (int m=0;m<MG;m++) Mv[m] = (mg0+m < SZM) ? Mv0[(mg0+m)*DIMS + d] : 0.f;

    // staging split across 8 waves; LDS base wave-uniform per issue.
    // w: 640 floats staged as 3x256 (over-read lands in adjacent valid ws, never consumed)
    #define STAGE(bi, t0)                                                          \
    {                                                                              \
        const float* Eb = Eg + (size_t)(t0)*DIMS;                                  \
        const float* Ab = Ag + (size_t)(t0)*DIMS;                                  \
        const float* Wb = Wg + (size_t)(t0)*64;                                    \
        for (int i = wid; i < CH*DIMS/256; i += 8){                                \
            gl_lds16(Eb + i*256 + lane*4, &e_lds[bi][i*256]);                      \
            gl_lds16(Ab + i*256 + lane*4, &a_lds[bi][i*256]);                      \
        }                                                                          \
        for (int i = wid; i < 3; i += 8){                                          \
            gl_lds16(Wb + i*256 + lane*4, &w_lds[bi][i*256]);                      \
        }                                                                          \
    }

    STAGE(0, 0)
    __syncthreads();

    float rts[CH];
    int cur = 0;
    for (int c = 0; c < NL/CH; ++c){
        // previous chunk: sub 0 combines with subs 1-3's rt_lds and stores.
        // rt_lds[cur^1] was published before the barrier at end of c-1;
        // subs write rt_lds[cur] this iteration -> no race (different buffer).
        if (c > 0 && sub == 0){
            #pragma unroll
            for (int s=0;s<CH;s++){
                float v = rts[s] + rt_lds[cur^1][0][s*DIMS+d]
                        + rt_lds[cur^1][1][s*DIMS+d] + rt_lds[cur^1][2][s*DIMS+d];
                prb[(size_t)((c-1)*CH+s)*DIMS] = f2bf(v);
            }
        }
        if (c+1 < NL/CH) STAGE(cur^1, (c+1)*CH)

        float ev[CH], av[CH];
        #pragma unroll
        for (int s=0;s<CH;s++){
            ev[s] = e_lds[cur][s*DIMS + d];
            av[s] = a_lds[cur][s*DIMS + d];
        }
        #pragma unroll
        for (int s=0;s<CH;s++){
            float rt0=0.f, rt1=0.f;
            #pragma unroll
            for (int m=0;m<MG;m++){
                float cc = w_lds[cur][s*64 + mg0 + m];  // wave-uniform -> broadcast
                float u  = fmaf(-ev[s], Mv[m], av[s]);
                if (m&1) rt1 = fmaf(cc, Mv[m], rt1);
                else     rt0 = fmaf(cc, Mv[m], rt0);
                Mv[m] = fmaf(cc, u, Mv[m]);
            }
            rts[s] = rt0+rt1;
        }
        if (sub > 0){
            #pragma unroll
            for (int s=0;s<CH;s++) rt_lds[cur][sub-1][s*DIMS+d] = rts[s];
        }
        __syncthreads();   // staging drained; rt_lds[cur] published; cur safe to reuse
        cur ^= 1;
    }
    if (sub == 0){
        #pragma unroll
        for (int s=0;s<CH;s++){
            float v = rts[s] + rt_lds[cur^1][0][s*DIMS+d]
                    + rt_lds[cur^1][1][s*DIMS+d] + rt_lds[cur^1][2][s*DIMS+d];
            prb[(size_t)((NL-CH)+s)*DIMS] = f2bf(v);
        }
    }
    #undef STAGE
}

// ---------------- fp: MFMA GEMM, A = [sum4(reads) | k] bf16 ----------------
__global__ __launch_bounds__(256) void fp_kernel(
    const u16* __restrict__ PRB, const u16* __restrict__ KB,
    const u16* __restrict__ Wfp,
    const float* __restrict__ bf, const float* __restrict__ Wp,
    const float* __restrict__ bp, float* __restrict__ out)
{
    __shared__ __align__(16) u16 sA[32][264];   // [token][0..127 reads | 128..255 k]
    __shared__ float pf[32][132];

    const int tid  = threadIdx.x;
    const int base = blockIdx.x * 32;

    {
        const int t  = tid >> 3;
        const int p8 = tid & 7;
        const size_t tok = (size_t)base + t;
        #pragma unroll
        for (int v=0; v<2; ++v){
            const int d0 = p8*16 + v*8;
            float s[8] = {0,0,0,0,0,0,0,0};
            #pragma unroll
            for (int g=0; g<NPR; ++g){
                u16x8 x = *(const u16x8*)(PRB + ((size_t)g*NTOK + tok)*DIMS + d0);
                #pragma unroll
                for (int j=0;j<8;j++) s[j] += bf2f(x[j]);
            }
            u16x8 o;
            #pragma unroll
            for (int j=0;j<8;j++) o[j] = f2bf(s[j]);
            *(u16x8*)&sA[t][d0] = o;
            *(u16x8*)&sA[t][128+d0] = *(const u16x8*)(KB + tok*DIMS + d0);
        }
    }
    __syncthreads();

    const int w    = tid >> 6;
    const int l    = tid & 63;
    const int l15  = l & 15;
    const int kgrp = (l >> 4) * 8;
    const int nb0  = 2*w, nb1 = 2*w+1;

    f32x4 c00={0,0,0,0},c01={0,0,0,0},c10={0,0,0,0},c11={0,0,0,0};
    #pragma unroll
    for (int ks=0; ks<8; ++ks){
        bf16x8 a0 = *(const bf16x8*)&sA[l15   ][ks*32+kgrp];
        bf16x8 a1 = *(const bf16x8*)&sA[16+l15][ks*32+kgrp];
        bf16x8 b0 = *(const bf16x8*)(Wfp + ((size_t)(ks*8+nb0)*64 + l)*8);
        bf16x8 b1 = *(const bf16x8*)(Wfp + ((size_t)(ks*8+nb1)*64 + l)*8);
        c00 = MFMA(a0,b0,c00); c01 = MFMA(a0,b1,c01);
        c10 = MFMA(a1,b0,c10); c11 = MFMA(a1,b1,c11);
    }
    {
        int cc0 = w*32 + l15, cc1 = w*32 + 16 + l15;
        float bf0 = bf[cc0], bf1 = bf[cc1];
        float wp0 = Wp[cc0], wp1 = Wp[cc1];
        #pragma unroll
        for (int rr=0; rr<4; ++rr){
            int r0 = (l>>4)*4 + rr;
            int r1 = 16 + r0;
            pf[r0][cc0] = tanhf(c00[rr]+bf0)*wp0;
            pf[r0][cc1] = tanhf(c01[rr]+bf1)*wp1;
            pf[r1][cc0] = tanhf(c10[rr]+bf0)*wp0;
            pf[r1][cc1] = tanhf(c11[rr]+bf1)*wp1;
        }
    }
    __syncthreads();

    {
        const int t  = tid >> 3;
        const int ml = tid & 7;
        float s = 0.f;
        #pragma unroll
        for (int j=0;j<16;j++) s += pf[t][ml + j*8];
        #pragma unroll
        for (int o=1;o<8;o<<=1) s += __shfl_xor(s, o);
        if (ml == 0) out[base+t] = sigmoidf_(s + bp[0]);
    }
}

extern "C" void kernel_launch(void* const* d_in, const int* in_sizes, int n_in,
                              void* d_out, int out_size, void* d_ws, size_t ws_size,
                              hipStream_t stream)
{
    const int*   q     = (const int*)  d_in[0];
    const int*   r     = (const int*)  d_in[1];
    /* d_in[2] = diff (unused) */
    const float* k_emb = (const float*)d_in[3];
    const float* v_emb = (const float*)d_in[4];
    const float* W1    = (const float*)d_in[5];
    const float* b1    = (const float*)d_in[6];
    const float* W2    = (const float*)d_in[7];
    const float* b2    = (const float*)d_in[8];
    const float* Mk    = (const float*)d_in[9];
    const float* Mv0   = (const float*)d_in[10];
    const float* We    = (const float*)d_in[11];
    const float* be    = (const float*)d_in[12];
    const float* Wa    = (const float*)d_in[13];
    const float* ba    = (const float*)d_in[14];
    const float* Wf    = (const float*)d_in[15];
    const float* bf    = (const float*)d_in[16];
    const float* Wp    = (const float*)d_in[17];
    const float* bp    = (const float*)d_in[18];

    float* ws  = (float*)d_ws;
    float* out = (float*)d_out;
    u16* KB  = (u16*)(ws + OFF_KBF);
    u16* PRB = (u16*)(ws + OFF_PRF);
    u16* pk  = (u16*)(ws + OFF_PKF);
    u16* W1p = pk + PK_W1;
    u16* W2p = pk + PK_W2;
    u16* Wep = pk + PK_WE;
    u16* Wap = pk + PK_WA;
    u16* Mkp = pk + PK_MK;
    u16* Wfp = pk + PK_WF;

    pack_kernel<<<100, 256, 0, stream>>>(W1,W2,We,Wa,Mk,Wf, W1p,W2p,Wep,Wap,Mkp,Wfp);
    prep_kernel<<<NTOK/32, 256, 0, stream>>>(q,r,k_emb,v_emb,b1,b2,be,ba,W1p,W2p,Wep,Wap,Mkp,ws,KB);
    scan_kernel<<<dim3(NB,NGQ), 512, 0, stream>>>(Mv0, ws, PRB);
    fp_kernel<<<NTOK/32, 256, 0, stream>>>(PRB, KB, Wfp, bf, Wp, bp, out);
}

// Round 24
// 61.156 us; speedup vs baseline: 1.0944x; 1.0556x over previous
//
#include <hip/hip_runtime.h>
#include <hip/hip_bf16.h>
#include <math.h>

#define NUMC 10000
#define DIMS 128
#define SZM  50
#define FD   512
#define NB   64
#define NL   200
#define NTOK (NB*NL)
#define NGQ  4      // group-quads in scan (blocks.y); 16 effective m-groups
#define MG   4      // m's per group (64 padded; w=0 beyond 49)
#define NPR  4      // combined partials stored / summed by fp
#define CH   8      // steps per staged chunk (scan): 25 chunks of 8

typedef unsigned short u16;
typedef __attribute__((ext_vector_type(8))) short bf16x8;
typedef __attribute__((ext_vector_type(8))) unsigned short u16x8;
typedef __attribute__((ext_vector_type(4))) float f32x4;

// ws layout (float offsets)
#define OFF_K   ((size_t)0)                           // (unused fp32 k region, kept for layout stability)
#define OFF_W   (OFF_K  + (size_t)NTOK*DIMS)          // [NTOK][64], m-major 0..49, 50..63 zeroed
#define OFF_E   (OFF_W  + (size_t)NTOK*64)
#define OFF_A   (OFF_E  + (size_t)NTOK*DIMS)
#define OFF_KBF (OFF_A  + (size_t)NTOK*DIMS)          // bf16 k [NTOK][128] (u16) = NTOK*64 floats
#define OFF_PRF (OFF_KBF+ (size_t)NTOK*64)            // bf16 partials [NPR][NTOK][128]
#define OFF_PKF (OFF_PRF+ (size_t)NTOK*512)           // packed bf16 weights (u16)
// u16 offsets within pack region:
#define PK_W1 0
#define PK_W2 65536      // 16 ks * 8 nb * 64 lanes * 8
#define PK_WE 131072
#define PK_WA 147456     // 4*8*64*8 = 16384 each
#define PK_MK 163840     // 4*4*64*8 = 8192
#define PK_WF 172032     // 8*8*64*8 = 32768

__device__ __forceinline__ float sigmoidf_(float x){ return 1.0f/(1.0f+expf(-x)); }

__device__ __forceinline__ u16 f2bf(float f){
    unsigned int b = __float_as_uint(f);
    b += 0x7fffu + ((b >> 16) & 1u);
    return (u16)(b >> 16);
}
__device__ __forceinline__ float bf2f(u16 h){
    unsigned int b = ((unsigned int)h) << 16;
    return __uint_as_float(b);
}
// async global->LDS, 16B per lane; LDS dest = uniform base + lane*16; global src per-lane
__device__ __forceinline__ void gl_lds16(const float* g, float* l){
    __builtin_amdgcn_global_load_lds(
        (const __attribute__((address_space(1))) unsigned int*)g,
        (__attribute__((address_space(3))) unsigned int*)l, 16, 0, 0);
}

// ---------------- pack kernel: W[K][128] fp32 -> B-fragment-order bf16 ----------------
__device__ __forceinline__ void pack_one(const float* __restrict__ W, u16* __restrict__ P, int u, int nbw){
    int l = u & 63; int t = u >> 6; int nb = t & (nbw-1); int ks = t / nbw;
    int col = nb*16 + (l & 15);
    int kb  = ks*32 + ((l >> 4) << 3);
    u16* dst = P + (size_t)u*8;
    #pragma unroll
    for (int j=0;j<8;j++) dst[j] = f2bf(W[(size_t)(kb+j)*DIMS + col]);
}

__global__ __launch_bounds__(256) void pack_kernel(
    const float* __restrict__ W1, const float* __restrict__ W2,
    const float* __restrict__ We, const float* __restrict__ Wa,
    const float* __restrict__ Mk, const float* __restrict__ Wf,
    u16* __restrict__ W1p, u16* __restrict__ W2p,
    u16* __restrict__ Wep, u16* __restrict__ Wap,
    u16* __restrict__ Mkp, u16* __restrict__ Wfp)
{
    int gid = blockIdx.x*256 + threadIdx.x;
    if      (gid <  8192) pack_one(W1, W1p, gid,        8);
    else if (gid < 16384) pack_one(W2, W2p, gid- 8192,  8);
    else if (gid < 18432) pack_one(We, Wep, gid-16384,  8);
    else if (gid < 20480) pack_one(Wa, Wap, gid-18432,  8);
    else if (gid < 21504){
        int u = gid - 20480;
        int l = u & 63; int t = u >> 6; int nb = t & 3; int ks = t >> 2;
        int col = nb*16 + (l & 15);
        int kb  = ks*32 + ((l >> 4) << 3);
        u16* dst = Mkp + (size_t)u*8;
        #pragma unroll
        for (int j=0;j<8;j++) dst[j] = (col < SZM) ? f2bf(Mk[(size_t)col*DIMS + kb + j]) : (u16)0;
    }
    else if (gid < 25600) pack_one(Wf, Wfp, gid-21504, 8);   // K=256
}

// ---------------- prep: MFMA GEMMs, coalesced XOR-swizzled A-gather staging (r22) ----------------
__device__ __forceinline__ bf16x8 cvt8(f32x4 a, f32x4 b){
    unsigned int r0,r1,r2,r3;
    asm("v_cvt_pk_bf16_f32 %0, %1, %2" : "=v"(r0) : "v"(a[0]), "v"(a[1]));
    asm("v_cvt_pk_bf16_f32 %0, %1, %2" : "=v"(r1) : "v"(a[2]), "v"(a[3]));
    asm("v_cvt_pk_bf16_f32 %0, %1, %2" : "=v"(r2) : "v"(b[0]), "v"(b[1]));
    asm("v_cvt_pk_bf16_f32 %0, %1, %2" : "=v"(r3) : "v"(b[2]), "v"(b[3]));
    union { unsigned int u[4]; bf16x8 v; } o;
    o.u[0]=r0; o.u[1]=r1; o.u[2]=r2; o.u[3]=r3;
    return o.v;
}
#define MFMA(a,b,c) __builtin_amdgcn_mfma_f32_16x16x32_bf16((a),(b),(c),0,0,0)

__global__ __launch_bounds__(256) void prep_kernel(
    const int* __restrict__ q, const int* __restrict__ r,
    const float* __restrict__ k_emb, const float* __restrict__ v_emb,
    const float* __restrict__ b1, const float* __restrict__ b2,
    const float* __restrict__ be, const float* __restrict__ ba,
    const u16* __restrict__ W1p, const u16* __restrict__ W2p,
    const u16* __restrict__ Wep, const u16* __restrict__ Wap,
    const u16* __restrict__ Mkp,
    float* __restrict__ ws, u16* __restrict__ KB)
{
    __shared__ __align__(16) char smem[32768];
    __shared__ int qi[32], xi[32];
    float (*afk)[2048] = (float(*)[2048])(smem);            // [2][2048] 16KB
    float (*afv)[2048] = (float(*)[2048])(smem + 16384);    // [2][2048] 16KB
    u16   (*skb)[144]  = (u16(*)[144])(smem);               // 9216B
    u16   (*svb)[144]  = (u16(*)[144])(smem + 9216);        // 9216B
    float (*lg)[68]    = (float(*)[68])(smem + 18432);      // 8704B

    const int tid  = threadIdx.x;
    const int base = blockIdx.x * 32;
    if (tid < 32){
        int qq = q[base+tid];
        qi[tid] = qq;
        xi[tid] = qq + NUMC * r[base+tid];
    }
    __syncthreads();

    const int w    = tid >> 6;
    const int l    = tid & 63;
    const int l15  = l & 15;

    const int tk0 = 8*w +     (l >> 4);
    const int tk1 = 8*w + 4 + (l >> 4);
    const int sl  = l & 15;
    const int f0  = sl ^ (tk0 & 7);
    const int f1  = sl ^ (tk1 & 7);
    const float* kst0 = k_emb + (size_t)qi[tk0]*FD + f0*4;
    const float* kst1 = k_emb + (size_t)qi[tk1]*FD + f1*4;
    const float* vst0 = v_emb + (size_t)xi[tk0]*FD + f0*4;
    const float* vst1 = v_emb + (size_t)xi[tk1]*FD + f1*4;

    #define PSTAGE(bi, c)                                                      \
    {                                                                          \
        gl_lds16(kst0 + (c)*64, &afk[bi][(w*2+0)*256]);                        \
        gl_lds16(kst1 + (c)*64, &afk[bi][(w*2+1)*256]);                        \
        gl_lds16(vst0 + (c)*64, &afv[bi][(w*2+0)*256]);                        \
        gl_lds16(vst1 + (c)*64, &afv[bi][(w*2+1)*256]);                        \
    }

    f32x4 kc00={0,0,0,0},kc01={0,0,0,0},kc10={0,0,0,0},kc11={0,0,0,0};
    f32x4 vc00={0,0,0,0},vc01={0,0,0,0},vc10={0,0,0,0},vc11={0,0,0,0};

    PSTAGE(0, 0)
    __syncthreads();

    const int kgrp = (l >> 4) * 8;
    const int nb0  = 2*w, nb1 = 2*w+1;
    const int x0 = l15*64;
    const int x1 = (16+l15)*64;
    const int sw = l15 & 7;

    int cur = 0;
    for (int c=0; c<8; ++c){
        if (c < 7) PSTAGE(cur^1, c+1)

        #pragma unroll
        for (int ksl=0; ksl<2; ++ksl){
            const int ksg = c*2 + ksl;
            const int f40 = ksl*8 + (l>>4)*2;
            const int o0 = ((f40  ) ^ sw)*4;
            const int o1 = ((f40+1) ^ sw)*4;
            f32x4 k0a = *(const f32x4*)&afk[cur][x0 + o0];
            f32x4 k0b = *(const f32x4*)&afk[cur][x0 + o1];
            f32x4 k1a = *(const f32x4*)&afk[cur][x1 + o0];
            f32x4 k1b = *(const f32x4*)&afk[cur][x1 + o1];
            f32x4 v0a = *(const f32x4*)&afv[cur][x0 + o0];
            f32x4 v0b = *(const f32x4*)&afv[cur][x0 + o1];
            f32x4 v1a = *(const f32x4*)&afv[cur][x1 + o0];
            f32x4 v1b = *(const f32x4*)&afv[cur][x1 + o1];
            bf16x8 ak0 = cvt8(k0a,k0b), ak1 = cvt8(k1a,k1b);
            bf16x8 av0 = cvt8(v0a,v0b), av1 = cvt8(v1a,v1b);
            bf16x8 b10 = *(const bf16x8*)(W1p + ((size_t)(ksg*8+nb0)*64 + l)*8);
            bf16x8 b11 = *(const bf16x8*)(W1p + ((size_t)(ksg*8+nb1)*64 + l)*8);
            bf16x8 b20 = *(const bf16x8*)(W2p + ((size_t)(ksg*8+nb0)*64 + l)*8);
            bf16x8 b21 = *(const bf16x8*)(W2p + ((size_t)(ksg*8+nb1)*64 + l)*8);
            kc00 = MFMA(ak0,b10,kc00); kc01 = MFMA(ak0,b11,kc01);
            kc10 = MFMA(ak1,b10,kc10); kc11 = MFMA(ak1,b11,kc11);
            vc00 = MFMA(av0,b20,vc00); vc01 = MFMA(av0,b21,vc01);
            vc10 = MFMA(av1,b20,vc10); vc11 = MFMA(av1,b21,vc11);
        }
        __syncthreads();
        cur ^= 1;
    }
    #undef PSTAGE

    {
        int c0 = w*32 + l15, c1 = w*32 + 16 + l15;
        float bk0 = b1[c0], bk1 = b1[c1], bv0 = b2[c0], bv1 = b2[c1];
        #pragma unroll
        for (int rr=0; rr<4; ++rr){
            int r0 = (l>>4)*4 + rr;
            int r1 = 16 + r0;
            u16 h;
            h = f2bf(kc00[rr]+bk0); skb[r0][c0]=h; KB[(size_t)(base+r0)*DIMS+c0]=h;
            h = f2bf(kc01[rr]+bk1); skb[r0][c1]=h; KB[(size_t)(base+r0)*DIMS+c1]=h;
            h = f2bf(kc10[rr]+bk0); skb[r1][c0]=h; KB[(size_t)(base+r1)*DIMS+c0]=h;
            h = f2bf(kc11[rr]+bk1); skb[r1][c1]=h; KB[(size_t)(base+r1)*DIMS+c1]=h;
            svb[r0][c0]=f2bf(vc00[rr]+bv0);
            svb[r0][c1]=f2bf(vc01[rr]+bv1);
            svb[r1][c0]=f2bf(vc10[rr]+bv0);
            svb[r1][c1]=f2bf(vc11[rr]+bv1);
        }
    }
    __syncthreads();

    {
        f32x4 lc0={0,0,0,0}, lc1={0,0,0,0};
        #pragma unroll
        for (int ks=0; ks<4; ++ks){
            bf16x8 a0 = *(const bf16x8*)&skb[l15   ][ks*32+kgrp];
            bf16x8 a1 = *(const bf16x8*)&skb[16+l15][ks*32+kgrp];
            bf16x8 bm = *(const bf16x8*)(Mkp + ((size_t)(ks*4+w)*64 + l)*8);
            lc0 = MFMA(a0,bm,lc0);
            lc1 = MFMA(a1,bm,lc1);
        }
        int cm = w*16 + l15;
        #pragma unroll
        for (int rr=0; rr<4; ++rr){
            int r0 = (l>>4)*4 + rr;
            lg[r0   ][cm] = lc0[rr];
            lg[16+r0][cm] = lc1[rr];
        }
    }

    {
        f32x4 ec00={0,0,0,0},ec01={0,0,0,0},ec10={0,0,0,0},ec11={0,0,0,0};
        f32x4 ac00={0,0,0,0},ac01={0,0,0,0},ac10={0,0,0,0},ac11={0,0,0,0};
        #pragma unroll
        for (int ks=0; ks<4; ++ks){
            bf16x8 a0 = *(const bf16x8*)&svb[l15   ][ks*32+kgrp];
            bf16x8 a1 = *(const bf16x8*)&svb[16+l15][ks*32+kgrp];
            bf16x8 e0 = *(const bf16x8*)(Wep + ((size_t)(ks*8+nb0)*64 + l)*8);
            bf16x8 e1 = *(const bf16x8*)(Wep + ((size_t)(ks*8+nb1)*64 + l)*8);
            bf16x8 a0w= *(const bf16x8*)(Wap + ((size_t)(ks*8+nb0)*64 + l)*8);
            bf16x8 a1w= *(const bf16x8*)(Wap + ((size_t)(ks*8+nb1)*64 + l)*8);
            ec00 = MFMA(a0,e0,ec00); ec01 = MFMA(a0,e1,ec01);
            ec10 = MFMA(a1,e0,ec10); ec11 = MFMA(a1,e1,ec11);
            ac00 = MFMA(a0,a0w,ac00); ac01 = MFMA(a0,a1w,ac01);
            ac10 = MFMA(a1,a0w,ac10); ac11 = MFMA(a1,a1w,ac11);
        }
        int c0 = w*32 + l15, c1 = w*32 + 16 + l15;
        float beE0 = be[c0], beE1 = be[c1], baA0 = ba[c0], baA1 = ba[c1];
        #pragma unroll
        for (int rr=0; rr<4; ++rr){
            int r0 = (l>>4)*4 + rr;
            int r1 = 16 + r0;
            ws[OFF_E+(size_t)(base+r0)*DIMS+c0] = sigmoidf_(ec00[rr]+beE0);
            ws[OFF_E+(size_t)(base+r0)*DIMS+c1] = sigmoidf_(ec01[rr]+beE1);
            ws[OFF_E+(size_t)(base+r1)*DIMS+c0] = sigmoidf_(ec10[rr]+beE0);
            ws[OFF_E+(size_t)(base+r1)*DIMS+c1] = sigmoidf_(ec11[rr]+beE1);
            ws[OFF_A+(size_t)(base+r0)*DIMS+c0] = tanhf(ac00[rr]+baA0);
            ws[OFF_A+(size_t)(base+r0)*DIMS+c1] = tanhf(ac01[rr]+baA1);
            ws[OFF_A+(size_t)(base+r1)*DIMS+c0] = tanhf(ac10[rr]+baA0);
            ws[OFF_A+(size_t)(base+r1)*DIMS+c1] = tanhf(ac11[rr]+baA1);
        }
    }
    __syncthreads();

    {
        const int t  = tid >> 3;
        const int ml = tid & 7;
        float v[7]; float mx = -1e30f;
        #pragma unroll
        for (int j=0;j<7;j++){
            int m = ml + j*8;
            float x = (m < SZM) ? lg[t][m] : -1e30f;
            v[j] = x; mx = fmaxf(mx, x);
        }
        #pragma unroll
        for (int o=1;o<8;o<<=1) mx = fmaxf(mx, __shfl_xor(mx, o));
        float ex[7]; float sm = 0.f;
        #pragma unroll
        for (int j=0;j<7;j++){
            int m = ml + j*8;
            ex[j] = (m < SZM) ? expf(v[j]-mx) : 0.f;
            sm += ex[j];
        }
        #pragma unroll
        for (int o=1;o<8;o<<=1) sm += __shfl_xor(sm, o);
        float inv = 1.f/sm;
        #pragma unroll
        for (int j=0;j<8;j++){
            int m = ml + j*8;
            float val = (j<7 && m<SZM) ? ex[j]*inv : 0.f;
            if (m < 64) ws[OFF_W + (size_t)(base+t)*64 + m] = val;
        }
    }
}

// ---------------- scan: NGQ=4 quad; balanced 4-way combine, W-sliced staging ----------------
// Changes vs r23: (1) ALL 4 subs write rt_lds (4 slices) and each sub
// combines+stores 2 of CH=8 steps -> worst-thread combine tail drops ~4x.
// (2) W staging slices the block's 16 m-columns only (1 gl_lds16/chunk,
// per-lane gather src; lanes 32-63 write harmless dups to unused slots).
// LDS 56 -> 50KB.
__global__ __launch_bounds__(512) void scan_kernel(const float* __restrict__ Mv0,
                                                   float* __restrict__ ws,
                                                   u16* __restrict__ PRB)
{
    __shared__ float e_lds[2][CH*DIMS];      // 8KB
    __shared__ float a_lds[2][CH*DIMS];      // 8KB
    __shared__ float w_lds[2][256];          // 2KB (sliced: [s][16 cols], slots 128+ dup)
    __shared__ float rt_lds[2][4][CH*DIMS];  // 32KB (all-subs combine, dbuf vs barrier)

    const int b    = blockIdx.x;
    const int gq   = blockIdx.y;             // group quad 0..3
    const int tid  = threadIdx.x;
    const int d    = tid & 127;
    const int sub  = tid >> 7;               // 0..3
    const int lane = tid & 63;
    const int wid  = tid >> 6;               // 0..7

    const float* Eg = ws + OFF_E + (size_t)b*NL*DIMS;
    const float* Ag = ws + OFF_A + (size_t)b*NL*DIMS;
    const float* Wg = ws + OFF_W + (size_t)b*NL*64;
    u16* prb = PRB + ((size_t)gq*NTOK + (size_t)b*NL)*DIMS + d;

    const int mg0 = (4*gq + sub)*MG;
    const int wcol = sub*MG;                 // local col of this sub's m's in the W slice
    float Mv[MG];
    #pragma unroll
    for (int m=0;m<MG;m++) Mv[m] = (mg0+m < SZM) ? Mv0[(mg0+m)*DIMS + d] : 0.f;

    // staging: waves 0-3 stage E (issue i=wid), waves 4-7 stage A; wave 0 also
    // stages the W slice (lane src: step (lane>>2)&7, cols 16gq+(lane&3)*4).
    #define STAGE(bi, t0)                                                          \
    {                                                                              \
        if (wid < 4){                                                              \
            gl_lds16(Eg + (size_t)(t0)*DIMS + wid*256 + lane*4,                    \
                     &e_lds[bi][wid*256]);                                         \
            if (wid == 0){                                                         \
                gl_lds16(Wg + (size_t)((t0) + ((lane>>2)&7))*64 + 16*gq            \
                            + (lane&3)*4, &w_lds[bi][0]);                          \
            }                                                                      \
        } else {                                                                   \
            gl_lds16(Ag + (size_t)(t0)*DIMS + (wid-4)*256 + lane*4,                \
                     &a_lds[bi][(wid-4)*256]);                                     \
        }                                                                          \
    }

    STAGE(0, 0)
    __syncthreads();

    float rts[CH];
    int cur = 0;
    for (int c = 0; c < NL/CH; ++c){
        // previous chunk: each sub combines 4 slices and stores ITS 2 steps.
        // rt_lds[cur^1] was published before the barrier at end of c-1;
        // all subs write rt_lds[cur] this iteration -> no race (other buffer).
        if (c > 0){
            #pragma unroll
            for (int j=0;j<2;j++){
                int s = sub*2 + j;
                float v = rt_lds[cur^1][0][s*DIMS+d] + rt_lds[cur^1][1][s*DIMS+d]
                        + rt_lds[cur^1][2][s*DIMS+d] + rt_lds[cur^1][3][s*DIMS+d];
                prb[(size_t)((c-1)*CH+s)*DIMS] = f2bf(v);
            }
        }
        if (c+1 < NL/CH) STAGE(cur^1, (c+1)*CH)

        float ev[CH], av[CH];
        #pragma unroll
        for (int s=0;s<CH;s++){
            ev[s] = e_lds[cur][s*DIMS + d];
            av[s] = a_lds[cur][s*DIMS + d];
        }
        #pragma unroll
        for (int s=0;s<CH;s++){
            float rt0=0.f, rt1=0.f;
            #pragma unroll
            for (int m=0;m<MG;m++){
                float cc = w_lds[cur][s*16 + wcol + m];  // wave-uniform -> broadcast
                float u  = fmaf(-ev[s], Mv[m], av[s]);
                if (m&1) rt1 = fmaf(cc, Mv[m], rt1);
                else     rt0 = fmaf(cc, Mv[m], rt0);
                Mv[m] = fmaf(cc, u, Mv[m]);
            }
            rts[s] = rt0+rt1;
        }
        #pragma unroll
        for (int s=0;s<CH;s++) rt_lds[cur][sub][s*DIMS+d] = rts[s];
        __syncthreads();   // staging drained; rt_lds[cur] published; cur safe to reuse
        cur ^= 1;
    }
    // final chunk's combine+store
    {
        #pragma unroll
        for (int j=0;j<2;j++){
            int s = sub*2 + j;
            float v = rt_lds[cur^1][0][s*DIMS+d] + rt_lds[cur^1][1][s*DIMS+d]
                    + rt_lds[cur^1][2][s*DIMS+d] + rt_lds[cur^1][3][s*DIMS+d];
            prb[(size_t)((NL-CH)+s)*DIMS] = f2bf(v);
        }
    }
    #undef STAGE
}

// ---------------- fp: MFMA GEMM, A = [sum4(reads) | k] bf16 ----------------
__global__ __launch_bounds__(256) void fp_kernel(
    const u16* __restrict__ PRB, const u16* __restrict__ KB,
    const u16* __restrict__ Wfp,
    const float* __restrict__ bf, const float* __restrict__ Wp,
    const float* __restrict__ bp, float* __restrict__ out)
{
    __shared__ __align__(16) u16 sA[32][264];   // [token][0..127 reads | 128..255 k]
    __shared__ float pf[32][132];

    const int tid  = threadIdx.x;
    const int base = blockIdx.x * 32;

    {
        const int t  = tid >> 3;
        const int p8 = tid & 7;
        const size_t tok = (size_t)base + t;
        #pragma unroll
        for (int v=0; v<2; ++v){
            const int d0 = p8*16 + v*8;
            float s[8] = {0,0,0,0,0,0,0,0};
            #pragma unroll
            for (int g=0; g<NPR; ++g){
                u16x8 x = *(const u16x8*)(PRB + ((size_t)g*NTOK + tok)*DIMS + d0);
                #pragma unroll
                for (int j=0;j<8;j++) s[j] += bf2f(x[j]);
            }
            u16x8 o;
            #pragma unroll
            for (int j=0;j<8;j++) o[j] = f2bf(s[j]);
            *(u16x8*)&sA[t][d0] = o;
            *(u16x8*)&sA[t][128+d0] = *(const u16x8*)(KB + tok*DIMS + d0);
        }
    }
    __syncthreads();

    const int w    = tid >> 6;
    const int l    = tid & 63;
    const int l15  = l & 15;
    const int kgrp = (l >> 4) * 8;
    const int nb0  = 2*w, nb1 = 2*w+1;

    f32x4 c00={0,0,0,0},c01={0,0,0,0},c10={0,0,0,0},c11={0,0,0,0};
    #pragma unroll
    for (int ks=0; ks<8; ++ks){
        bf16x8 a0 = *(const bf16x8*)&sA[l15   ][ks*32+kgrp];
        bf16x8 a1 = *(const bf16x8*)&sA[16+l15][ks*32+kgrp];
        bf16x8 b0 = *(const bf16x8*)(Wfp + ((size_t)(ks*8+nb0)*64 + l)*8);
        bf16x8 b1 = *(const bf16x8*)(Wfp + ((size_t)(ks*8+nb1)*64 + l)*8);
        c00 = MFMA(a0,b0,c00); c01 = MFMA(a0,b1,c01);
        c10 = MFMA(a1,b0,c10); c11 = MFMA(a1,b1,c11);
    }
    {
        int cc0 = w*32 + l15, cc1 = w*32 + 16 + l15;
        float bf0 = bf[cc0], bf1 = bf[cc1];
        float wp0 = Wp[cc0], wp1 = Wp[cc1];
        #pragma unroll
        for (int rr=0; rr<4; ++rr){
            int r0 = (l>>4)*4 + rr;
            int r1 = 16 + r0;
            pf[r0][cc0] = tanhf(c00[rr]+bf0)*wp0;
            pf[r0][cc1] = tanhf(c01[rr]+bf1)*wp1;
            pf[r1][cc0] = tanhf(c10[rr]+bf0)*wp0;
            pf[r1][cc1] = tanhf(c11[rr]+bf1)*wp1;
        }
    }
    __syncthreads();

    {
        const int t  = tid >> 3;
        const int ml = tid & 7;
        float s = 0.f;
        #pragma unroll
        for (int j=0;j<16;j++) s += pf[t][ml + j*8];
        #pragma unroll
        for (int o=1;o<8;o<<=1) s += __shfl_xor(s, o);
        if (ml == 0) out[base+t] = sigmoidf_(s + bp[0]);
    }
}

extern "C" void kernel_launch(void* const* d_in, const int* in_sizes, int n_in,
                              void* d_out, int out_size, void* d_ws, size_t ws_size,
                              hipStream_t stream)
{
    const int*   q     = (const int*)  d_in[0];
    const int*   r     = (const int*)  d_in[1];
    /* d_in[2] = diff (unused) */
    const float* k_emb = (const float*)d_in[3];
    const float* v_emb = (const float*)d_in[4];
    const float* W1    = (const float*)d_in[5];
    const float* b1    = (const float*)d_in[6];
    const float* W2    = (const float*)d_in[7];
    const float* b2    = (const float*)d_in[8];
    const float* Mk    = (const float*)d_in[9];
    const float* Mv0   = (const float*)d_in[10];
    const float* We    = (const float*)d_in[11];
    const float* be    = (const float*)d_in[12];
    const float* Wa    = (const float*)d_in[13];
    const float* ba    = (const float*)d_in[14];
    const float* Wf    = (const float*)d_in[15];
    const float* bf    = (const float*)d_in[16];
    const float* Wp    = (const float*)d_in[17];
    const float* bp    = (const float*)d_in[18];

    float* ws  = (float*)d_ws;
    float* out = (float*)d_out;
    u16* KB  = (u16*)(ws + OFF_KBF);
    u16* PRB = (u16*)(ws + OFF_PRF);
    u16* pk  = (u16*)(ws + OFF_PKF);
    u16* W1p = pk + PK_W1;
    u16* W2p = pk + PK_W2;
    u16* Wep = pk + PK_WE;
    u16* Wap = pk + PK_WA;
    u16* Mkp = pk + PK_MK;
    u16* Wfp = pk + PK_WF;

    pack_kernel<<<100, 256, 0, stream>>>(W1,W2,We,Wa,Mk,Wf, W1p,W2p,Wep,Wap,Mkp,Wfp);
    prep_kernel<<<NTOK/32, 256, 0, stream>>>(q,r,k_emb,v_emb,b1,b2,be,ba,W1p,W2p,Wep,Wap,Mkp,ws,KB);
    scan_kernel<<<dim3(NB,NGQ), 512, 0, stream>>>(Mv0, ws, PRB);
    fp_kernel<<<NTOK/32, 256, 0, stream>>>(PRB, KB, Wfp, bf, Wp, bp, out);
}